// Round 13
// baseline (409.030 us; speedup 1.0000x reference)
//
#include <hip/hip_runtime.h>
#include <cstdint>
#include <cstddef>

// Problem constants
#define D_    512
#define H_    4
#define DH_   128
#define FFN_  128
#define L_    4
#define B_    8
#define T_    1025
#define U_    1024
#define NSEG_ 256
#define R_    256
#define TOT_  1280            // R + U
#define M_    (B_*TOT_)       // 10240 rows
#define CH_   1536            // QKV channels

typedef __attribute__((ext_vector_type(8))) short bf16x8;
typedef __attribute__((ext_vector_type(4))) float f32x4;
typedef unsigned short u16;

__device__ __forceinline__ u16 f2bf(float f) {
  unsigned u = __builtin_bit_cast(unsigned, f);
  u += 0x7fff + ((u >> 16) & 1);           // round-to-nearest-even
  return (u16)(u >> 16);
}
__device__ __forceinline__ float bf2f(u16 h) {
  unsigned u = ((unsigned)h) << 16;
  return __builtin_bit_cast(float, u);
}

__device__ __forceinline__ void gload_lds16(const void* g, void* l) {
  __builtin_amdgcn_global_load_lds(
      (const __attribute__((address_space(1))) unsigned*)g,
      (__attribute__((address_space(3))) unsigned*)l, 16, 0, 0);
}

#define QSCALE 0.08838834764831845f   // 128^-0.5, folded into Wq/bq

#define CVT_BLOCKS 4614
#define SETUP_GRID (CVT_BLOCKS + M_)   // 4614 cvt blocks + 10240 gather rows

// ---------------------------------------------------------------------------
// merged one-shot setup: weight cvt/pack (blocks 0..4613) + gather+LN-in(0)
// (blocks 4614..14853). Wq/bq are pre-scaled by QSCALE so attention skips it.
// ---------------------------------------------------------------------------
__global__ __launch_bounds__(256)
void cvt_gather_k(const float* __restrict__ Wq, const float* __restrict__ Wkv,
                  const float* __restrict__ Wo, const float* __restrict__ W1,
                  const float* __restrict__ W2, const float* __restrict__ bq,
                  const float* __restrict__ bkv,
                  u16* __restrict__ WQKVb, u16* __restrict__ Wob,
                  u16* __restrict__ W1b, u16* __restrict__ W2b,
                  float* __restrict__ bQKV,
                  const float* __restrict__ x, const float* __restrict__ g,
                  const float* __restrict__ bb, float* __restrict__ X,
                  u16* __restrict__ LNb) {
  __shared__ float red[10];
  const int bid = blockIdx.x;
  const int tid = threadIdx.x;

  if (bid >= CVT_BLOCKS) {
    // ---- gather + LN-in(layer 0) ----
    int row = bid - CVT_BLOCKS;
    int b = row / TOT_, p = row % TOT_;
    int t = (p < R_) ? ((p < R_ - 1) ? 4 * (p + 1) : (T_ - 1)) : (p - R_);
    const float* xr = x + ((size_t)b * T_ + t) * D_;
    float e0 = xr[tid], e1 = xr[tid + 256];
    X[(size_t)row * D_ + tid] = e0;
    X[(size_t)row * D_ + tid + 256] = e1;
    float s = e0 + e1, ss = e0 * e0 + e1 * e1;
#pragma unroll
    for (int off = 32; off > 0; off >>= 1) {
      s  += __shfl_down(s, off);
      ss += __shfl_down(ss, off);
    }
    int wid = tid >> 6, lane = tid & 63;
    if (lane == 0) { red[wid] = s; red[4 + wid] = ss; }
    __syncthreads();
    if (tid == 0) {
      float S = red[0] + red[1] + red[2] + red[3];
      float SS = red[4] + red[5] + red[6] + red[7];
      float mu = S * (1.0f / D_);
      float var = SS * (1.0f / D_) - mu * mu;
      if (var < 0.f) var = 0.f;
      red[8] = mu; red[9] = rsqrtf(var + 1e-5f);
    }
    __syncthreads();
    float mu = red[8], rs = red[9];
    u16* yr = LNb + (size_t)row * D_;
    yr[tid]       = f2bf((e0 - mu) * rs * g[tid]       + bb[tid]);
    yr[tid + 256] = f2bf((e1 - mu) * rs * g[tid + 256] + bb[tid + 256]);
    return;
  }

  // ---- weight conversion / packing ----
  int i4 = bid * 256 + tid;
  if (i4 < 786432) {                        // WQKV: 3,145,728 elems
    int e = i4 * 4;
    int l = e / 786432;
    int rem = e - l * 786432;
    int n = rem >> 9, k = rem & 511;
    const float* src = (n < 512) ? (Wq + (size_t)l * 262144 + n * 512 + k)
                                 : (Wkv + (size_t)l * 524288 + (n - 512) * 512 + k);
    float4 v = *(const float4*)src;
    if (n < 512) { v.x *= QSCALE; v.y *= QSCALE; v.z *= QSCALE; v.w *= QSCALE; }
    ushort4 o; o.x = f2bf(v.x); o.y = f2bf(v.y); o.z = f2bf(v.z); o.w = f2bf(v.w);
    *(ushort4*)(WQKVb + e) = o;
  } else if (i4 < 1048576) {                // Wo
    int e = (i4 - 786432) * 4;
    float4 v = *(const float4*)(Wo + e);
    ushort4 o; o.x = f2bf(v.x); o.y = f2bf(v.y); o.z = f2bf(v.z); o.w = f2bf(v.w);
    *(ushort4*)(Wob + e) = o;
  } else if (i4 < 1114112) {                // W1
    int e = (i4 - 1048576) * 4;
    float4 v = *(const float4*)(W1 + e);
    ushort4 o; o.x = f2bf(v.x); o.y = f2bf(v.y); o.z = f2bf(v.z); o.w = f2bf(v.w);
    *(ushort4*)(W1b + e) = o;
  } else if (i4 < 1179648) {                // W2
    int e = (i4 - 1114112) * 4;
    float4 v = *(const float4*)(W2 + e);
    ushort4 o; o.x = f2bf(v.x); o.y = f2bf(v.y); o.z = f2bf(v.z); o.w = f2bf(v.w);
    *(ushort4*)(W2b + e) = o;
  } else if (i4 < 1181184) {                // bias: 6144 elems
    int e = (i4 - 1179648) * 4;
    int l = e / 1536, n = e - l * 1536;
#pragma unroll
    for (int t = 0; t < 4; ++t) {
      int nn = n + t;
      bQKV[e + t] = (nn < 512) ? bq[l * 512 + nn] * QSCALE
                               : bkv[l * 1024 + (nn - 512)];
    }
  }
}

// ---------------------------------------------------------------------------
// bf16 MFMA GEMM, m97-style (128x128 tile, BK=32, 4 waves), XCD-swizzled.
// QKV projection: M=10240, N=1536, K=512. xcd=bid&7 owns 10 row-stripes
// x 12 col-blocks -> A chunk 1.28MB L2-resident per XCD.
// ---------------------------------------------------------------------------
#define GBK 32

__global__ __launch_bounds__(256)
void gemm_qkv(const u16* __restrict__ A, const u16* __restrict__ Bw,
              const float* __restrict__ bias, u16* __restrict__ Cout) {
  __shared__ __align__(16) u16 As[128 * GBK];
  __shared__ __align__(16) u16 Bs[128 * GBK];
  const int tid = threadIdx.x;
  const int wid = tid >> 6;
  const int lane = tid & 63;
  const int bid = blockIdx.x;
  const int xcd = bid & 7;
  const int t = bid >> 3;                 // 0..119
  const int cb = t % 12;
  const int rb = xcd * 10 + t / 12;
  const int bm = rb * 128;
  const int bn = cb * 128;
  const int wr = wid >> 1, wc = wid & 1;

  const int srow = tid >> 2;
  const int skoff = (tid & 3) << 3;

  f32x4 acc[4][4] = {};

  const u16* Ag0 = A  + (size_t)(bm + srow)      * D_ + skoff;
  const u16* Ag1 = A  + (size_t)(bm + 64 + srow) * D_ + skoff;
  const u16* Bg0 = Bw + (size_t)(bn + srow)      * D_ + skoff;
  const u16* Bg1 = Bw + (size_t)(bn + 64 + srow) * D_ + skoff;
  u16* AsW0 = &As[(size_t)(wid * 16)      * GBK];
  u16* AsW1 = &As[(size_t)(64 + wid * 16) * GBK];
  u16* BsW0 = &Bs[(size_t)(wid * 16)      * GBK];
  u16* BsW1 = &Bs[(size_t)(64 + wid * 16) * GBK];

  const int lrow = lane & 15;
  const int lko  = (lane >> 4) * 16;

  for (int k0 = 0; k0 < D_; k0 += GBK) {
    __syncthreads();
    gload_lds16(Ag0 + k0, AsW0);
    gload_lds16(Ag1 + k0, AsW1);
    gload_lds16(Bg0 + k0, BsW0);
    gload_lds16(Bg1 + k0, BsW1);
    __syncthreads();

    bf16x8 afrag[4], bfrag[4];
#pragma unroll
    for (int m = 0; m < 4; ++m) {
      int row = wr * 64 + m * 16 + lrow;
      afrag[m] = *(const bf16x8*)((const char*)As + row * (GBK * 2) + lko);
    }
#pragma unroll
    for (int n = 0; n < 4; ++n) {
      int col = wc * 64 + n * 16 + lrow;
      bfrag[n] = *(const bf16x8*)((const char*)Bs + col * (GBK * 2) + lko);
    }
#pragma unroll
    for (int m = 0; m < 4; ++m)
#pragma unroll
      for (int n = 0; n < 4; ++n)
        acc[m][n] = __builtin_amdgcn_mfma_f32_16x16x32_bf16(
            afrag[m], bfrag[n], acc[m][n], 0, 0, 0);
  }

  const int lcol  = lane & 15;
  const int lrow4 = (lane >> 4) * 4;
#pragma unroll
  for (int m = 0; m < 4; ++m) {
    int rowbase = bm + wr * 64 + m * 16 + lrow4;
#pragma unroll
    for (int n = 0; n < 4; ++n) {
      int col = bn + wc * 64 + n * 16 + lcol;
      float bv = bias[col];
#pragma unroll
      for (int j = 0; j < 4; ++j) {
        int row = rowbase + j;
        Cout[(size_t)row * CH_ + col] = f2bf(acc[m][n][j] + bv);
      }
    }
  }
}

// ---------------------------------------------------------------------------
// O-proj: pure N-tiled GEMM + residual, fp32 out (in-place X).
// 128x128 tile, 4 waves, grid 320 = 8 xcd x 4 cb x 10 rb.
// ---------------------------------------------------------------------------
__global__ __launch_bounds__(256)
void gemm_oproj(const u16* __restrict__ A, const u16* __restrict__ Bw,
                const float* __restrict__ bias, float* __restrict__ Xio) {
  __shared__ __align__(16) u16 As[128 * GBK];
  __shared__ __align__(16) u16 Bs[128 * GBK];
  const int tid = threadIdx.x;
  const int wid = tid >> 6;
  const int lane = tid & 63;
  const int bid = blockIdx.x;
  const int xcd = bid & 7;
  const int t = bid >> 3;                 // 0..39
  const int cb = t & 3;
  const int rb = xcd * 10 + (t >> 2);
  const int bm = rb * 128;
  const int bn = cb * 128;
  const int wr = wid >> 1, wc = wid & 1;

  const int srow = tid >> 2;
  const int skoff = (tid & 3) << 3;

  f32x4 acc[4][4] = {};

  const u16* Ag0 = A  + (size_t)(bm + srow)      * D_ + skoff;
  const u16* Ag1 = A  + (size_t)(bm + 64 + srow) * D_ + skoff;
  const u16* Bg0 = Bw + (size_t)(bn + srow)      * D_ + skoff;
  const u16* Bg1 = Bw + (size_t)(bn + 64 + srow) * D_ + skoff;
  u16* AsW0 = &As[(size_t)(wid * 16)      * GBK];
  u16* AsW1 = &As[(size_t)(64 + wid * 16) * GBK];
  u16* BsW0 = &Bs[(size_t)(wid * 16)      * GBK];
  u16* BsW1 = &Bs[(size_t)(64 + wid * 16) * GBK];

  const int lrow = lane & 15;
  const int lko  = (lane >> 4) * 16;

  for (int k0 = 0; k0 < D_; k0 += GBK) {
    __syncthreads();
    gload_lds16(Ag0 + k0, AsW0);
    gload_lds16(Ag1 + k0, AsW1);
    gload_lds16(Bg0 + k0, BsW0);
    gload_lds16(Bg1 + k0, BsW1);
    __syncthreads();

    bf16x8 afrag[4], bfrag[4];
#pragma unroll
    for (int m = 0; m < 4; ++m) {
      int row = wr * 64 + m * 16 + lrow;
      afrag[m] = *(const bf16x8*)((const char*)As + row * (GBK * 2) + lko);
    }
#pragma unroll
    for (int n = 0; n < 4; ++n) {
      int col = wc * 64 + n * 16 + lrow;
      bfrag[n] = *(const bf16x8*)((const char*)Bs + col * (GBK * 2) + lko);
    }
#pragma unroll
    for (int m = 0; m < 4; ++m)
#pragma unroll
      for (int n = 0; n < 4; ++n)
        acc[m][n] = __builtin_amdgcn_mfma_f32_16x16x32_bf16(
            afrag[m], bfrag[n], acc[m][n], 0, 0, 0);
  }

  const int lcol  = lane & 15;
  const int lrow4 = (lane >> 4) * 4;
#pragma unroll
  for (int m = 0; m < 4; ++m) {
    int rowbase = bm + wr * 64 + m * 16 + lrow4;
#pragma unroll
    for (int n = 0; n < 4; ++n) {
      int col = bn + wc * 64 + n * 16 + lcol;
      float bv = bias[col];
#pragma unroll
      for (int j = 0; j < 4; ++j) {
        size_t idx = (size_t)(rowbase + j) * D_ + col;
        Xio[idx] = acc[m][n][j] + bv + Xio[idx];
      }
    }
  }
}

// ---------------------------------------------------------------------------
// Fused FFN: LN_ff (register prologue) -> FFN1(relu, H in regs->LDS) ->
// FFN2 + residual + LN_out (+ LN_in next). 16-row tiles, grid 640.
// MODE 1 (l<3): LN1 -> Xout fp32; LN2 -> OutBf bf16.   MODE 2: LN1 only.
// ---------------------------------------------------------------------------
template <int MODE>
__global__ __launch_bounds__(256)
void ffn_fused(const float* __restrict__ X,
               const float* __restrict__ gff, const float* __restrict__ bff,
               const u16* __restrict__ W1, const float* __restrict__ b1,
               const u16* __restrict__ W2, const float* __restrict__ b2,
               const float* __restrict__ g1, const float* __restrict__ b1o,
               const float* __restrict__ g2, const float* __restrict__ b2i,
               float* __restrict__ Xout, u16* __restrict__ OutBf) {
  __shared__ __align__(16) u16 Bs[512 * 32];    // 32KB: W1 (first 8KB) / W2
  __shared__ __align__(16) u16 Aln[16 * 512];   // 16KB swizzled; Hs overlays
  __shared__ float wsum[4][16], wss[4][16], mu_s[16], rs_s[16];
  u16* Hs = Aln;                                // 4KB overlay (post phase A)
  const int tid = threadIdx.x;
  const int wid = tid >> 6, lane = tid & 63;
  const int bm = blockIdx.x * 16;
  const int r  = tid >> 4;            // 0..15 row in tile
  const int jj = tid & 15;            // 16 lanes per row

  // ---- LN_ff prologue (in registers) ----
  {
    const float* xr = X + (size_t)(bm + r) * D_ + jj * 32;
    float v[32];
    float s = 0.f, ss = 0.f;
#pragma unroll
    for (int i = 0; i < 8; ++i) {
      float4 q = *(const float4*)(xr + i * 4);
      v[i * 4 + 0] = q.x; v[i * 4 + 1] = q.y;
      v[i * 4 + 2] = q.z; v[i * 4 + 3] = q.w;
      s  += q.x + q.y + q.z + q.w;
      ss += q.x * q.x + q.y * q.y + q.z * q.z + q.w * q.w;
    }
#pragma unroll
    for (int off = 1; off < 16; off <<= 1) {
      s  += __shfl_xor(s, off);
      ss += __shfl_xor(ss, off);
    }
    float mu = s * (1.0f / D_);
    float var = ss * (1.0f / D_) - mu * mu;
    if (var < 0.f) var = 0.f;
    float rs = rsqrtf(var + 1e-5f);
    char* Ab = (char*)Aln;
#pragma unroll
    for (int i = 0; i < 8; ++i) {
      int c0 = jj * 32 + i * 4;
      float4 g4 = *(const float4*)(gff + c0);
      float4 b4 = *(const float4*)(bff + c0);
      ushort4 o;
      o.x = f2bf((v[i * 4 + 0] - mu) * rs * g4.x + b4.x);
      o.y = f2bf((v[i * 4 + 1] - mu) * rs * g4.y + b4.y);
      o.z = f2bf((v[i * 4 + 2] - mu) * rs * g4.z + b4.z);
      o.w = f2bf((v[i * 4 + 3] - mu) * rs * g4.w + b4.w);
      int byteoff = (r * 1024 + c0 * 2) ^ ((r & 7) << 4);
      *(ushort4*)(Ab + byteoff) = o;
    }
  }
  __syncthreads();

  // ---- phase A: H = relu(LN_ff @ W1^T + b1), H in registers ----
  const int lrow = lane & 15;
  const int lko  = (lane >> 4) << 4;   // bytes
  const int l4 = lane >> 2;
  const int k8 = (lane & 3) << 3;
  f32x4 accA[2] = {};

  for (int k0 = 0; k0 < D_; k0 += 32) {
    if (k0) __syncthreads();
#pragma unroll
    for (int p = 0; p < 2; ++p) {
      int rowb = wid * 32 + p * 16 + l4;
      gload_lds16(W1 + (size_t)rowb * D_ + k0 + k8,
                  (char*)Bs + (wid * 32 + p * 16) * 64);
    }
    __syncthreads();
    bf16x8 af = *(const bf16x8*)((const char*)Aln +
                  ((lrow * 1024 + k0 * 2 + lko) ^ ((lrow & 7) << 4)));
    bf16x8 bf[2];
#pragma unroll
    for (int n = 0; n < 2; ++n)
      bf[n] = *(const bf16x8*)((const char*)Bs + (wid * 32 + n * 16 + lrow) * 64 + lko);
#pragma unroll
    for (int n = 0; n < 2; ++n)
      accA[n] = __builtin_amdgcn_mfma_f32_16x16x32_bf16(af, bf[n], accA[n], 0, 0, 0);
  }

  const int lcol = lane & 15;
  const int lr4 = (lane >> 4) * 4;
  __syncthreads();                     // all Aln/Bs reads complete

  // ---- hand H to LDS (bias + relu, swizzled; overlays Aln) ----
#pragma unroll
  for (int n = 0; n < 2; ++n) {
    int col = wid * 32 + n * 16 + lcol;
    float bv = b1[col];
#pragma unroll
    for (int j = 0; j < 4; ++j) {
      int rr = lr4 + j;
      float hv = fmaxf(accA[n][j] + bv, 0.f);
      int byteoff = (rr * 256 + col * 2) ^ ((rr & 7) << 4);
      *(u16*)((char*)Hs + byteoff) = f2bf(hv);
    }
  }

  // ---- phase B: FFN2 + residual + LN_out (+ LN_in) ----
  f32x4 acc[8] = {};
  for (int k0 = 0; k0 < FFN_; k0 += 32) {
    __syncthreads();                   // k0=0: Hs visible; else: reads done
#pragma unroll
    for (int p = 0; p < 8; ++p) {
      int row = wid * 128 + p * 16 + l4;
      gload_lds16(W2 + (size_t)row * FFN_ + k0 + k8,
                  (char*)Bs + (wid * 128 + p * 16) * 64);
    }
    __syncthreads();

    bf16x8 af = *(const bf16x8*)((const char*)Hs +
                  ((lrow * 256 + k0 * 2 + lko) ^ ((lrow & 7) << 4)));
    bf16x8 bf[8];
#pragma unroll
    for (int n = 0; n < 8; ++n)
      bf[n] = *(const bf16x8*)((const char*)Bs + (wid * 128 + n * 16 + lrow) * 64 + lko);
#pragma unroll
    for (int n = 0; n < 8; ++n)
      acc[n] = __builtin_amdgcn_mfma_f32_16x16x32_bf16(af, bf[n], acc[n], 0, 0, 0);
  }

  // ---- bias + residual ----
#pragma unroll
  for (int n = 0; n < 8; ++n) {
    int col = wid * 128 + n * 16 + lcol;
    float bv = b2[col];
#pragma unroll
    for (int j = 0; j < 4; ++j) {
      int row = bm + lr4 + j;
      acc[n][j] = acc[n][j] + bv + X[(size_t)row * D_ + col];
    }
  }

  // ---- LN pass 1 (ln_out) ----
  {
    float s0[4] = {}, s1[4] = {};
#pragma unroll
    for (int n = 0; n < 8; ++n)
#pragma unroll
      for (int j = 0; j < 4; ++j) {
        float v = acc[n][j];
        s0[j] += v; s1[j] += v * v;
      }
#pragma unroll
    for (int off = 1; off < 16; off <<= 1)
#pragma unroll
      for (int j = 0; j < 4; ++j) {
        s0[j] += __shfl_xor(s0[j], off);
        s1[j] += __shfl_xor(s1[j], off);
      }
    if ((lane & 15) == 0) {
#pragma unroll
      for (int j = 0; j < 4; ++j) {
        wsum[wid][lr4 + j] = s0[j]; wss[wid][lr4 + j] = s1[j];
      }
    }
  }
  __syncthreads();
  if (tid < 16) {
    float S  = wsum[0][tid] + wsum[1][tid] + wsum[2][tid] + wsum[3][tid];
    float SS = wss[0][tid] + wss[1][tid] + wss[2][tid] + wss[3][tid];
    float mu = S * (1.0f / D_);
    float var = SS * (1.0f / D_) - mu * mu;
    if (var < 0.f) var = 0.f;
    mu_s[tid] = mu; rs_s[tid] = rsqrtf(var + 1e-5f);
  }
  __syncthreads();

  float gg[8], bv2[8];
#pragma unroll
  for (int n = 0; n < 8; ++n) {
    int col = wid * 128 + n * 16 + lcol;
    gg[n] = g1[col]; bv2[n] = b1o[col];
  }
#pragma unroll
  for (int n = 0; n < 8; ++n) {
    int col = wid * 128 + n * 16 + lcol;
#pragma unroll
    for (int j = 0; j < 4; ++j) {
      int rr = lr4 + j;
      int row = bm + rr;
      float ln = (acc[n][j] - mu_s[rr]) * rs_s[rr] * gg[n] + bv2[n];
      Xout[(size_t)row * D_ + col] = ln;
      acc[n][j] = ln;
    }
  }

  if (MODE == 1) {
    // ---- LN pass 2 (ln_in next layer) ----
    __syncthreads();
    {
      float s0[4] = {}, s1[4] = {};
#pragma unroll
      for (int n = 0; n < 8; ++n)
#pragma unroll
        for (int j = 0; j < 4; ++j) {
          float v = acc[n][j];
          s0[j] += v; s1[j] += v * v;
        }
#pragma unroll
      for (int off = 1; off < 16; off <<= 1)
#pragma unroll
        for (int j = 0; j < 4; ++j) {
          s0[j] += __shfl_xor(s0[j], off);
          s1[j] += __shfl_xor(s1[j], off);
        }
      if ((lane & 15) == 0) {
#pragma unroll
        for (int j = 0; j < 4; ++j) {
          wsum[wid][lr4 + j] = s0[j]; wss[wid][lr4 + j] = s1[j];
        }
      }
    }
    __syncthreads();
    if (tid < 16) {
      float S  = wsum[0][tid] + wsum[1][tid] + wsum[2][tid] + wsum[3][tid];
      float SS = wss[0][tid] + wss[1][tid] + wss[2][tid] + wss[3][tid];
      float mu = S * (1.0f / D_);
      float var = SS * (1.0f / D_) - mu * mu;
      if (var < 0.f) var = 0.f;
      mu_s[tid] = mu; rs_s[tid] = rsqrtf(var + 1e-5f);
    }
    __syncthreads();
#pragma unroll
    for (int n = 0; n < 8; ++n) {
      int col = wid * 128 + n * 16 + lcol;
      gg[n] = g2[col]; bv2[n] = b2i[col];
    }
#pragma unroll
    for (int n = 0; n < 8; ++n) {
      int col = wid * 128 + n * 16 + lcol;
#pragma unroll
      for (int j = 0; j < 4; ++j) {
        int rr = lr4 + j;
        int row = bm + rr;
        float ln = (acc[n][j] - mu_s[rr]) * rs_s[rr] * gg[n] + bv2[n];
        OutBf[(size_t)row * D_ + col] = f2bf(ln);
      }
    }
  }
}

// ---------------------------------------------------------------------------
// Block-diagonal attention reading fused QKV (stride 1536).
// Q stored f32 in LDS (scale pre-folded into Wq/bq); K,V stored bf16
// (21KB total LDS -> better residency for this latency-bound kernel).
// One block per (b, seg); wave h = head h. Segment rows: {s, 256+4s..+3}.
// ---------------------------------------------------------------------------
#define QLD 516
#define KLD 528   // u16 stride
__global__ __launch_bounds__(256)
void attn_k(const u16* __restrict__ QKV, u16* __restrict__ O) {
  int bs = blockIdx.x;
  int b = bs >> 8, s = bs & 255;
  __shared__ float Qs[5][QLD];
  __shared__ __align__(16) u16 Ks[5][KLD];
  __shared__ __align__(16) u16 Vs[5][KLD];
  __shared__ float P[H_][5][5];
  int tid = threadIdx.x;
  int rows[5];
  rows[0] = s;
#pragma unroll
  for (int i = 1; i < 5; ++i) rows[i] = R_ + 4 * s + (i - 1);
  // 960 chunks of 8 bf16: mtx (Q/K/V) x 5 rows x 64 chunks
  for (int idx = tid; idx < 960; idx += 256) {
    int mtx = idx / 320;
    int rem = idx - mtx * 320;
    int i = rem >> 6, c8 = rem & 63;
    size_t base = ((size_t)b * TOT_ + rows[i]) * CH_ + mtx * 512 + c8 * 8;
    bf16x8 v = *(const bf16x8*)(QKV + base);
    if (mtx == 0) {
      float* dst = &Qs[i][c8 * 8];
#pragma unroll
      for (int t = 0; t < 8; ++t) dst[t] = bf2f((u16)v[t]);
    } else if (mtx == 1) {
      *(bf16x8*)((char*)&Ks[i][0] + c8 * 16) = v;
    } else {
      *(bf16x8*)((char*)&Vs[i][0] + c8 * 16) = v;
    }
  }
  __syncthreads();
  int h = tid >> 6, lane = tid & 63;
  if (lane < 25) {
    int i = lane / 5, j = lane % 5;
    float sum = 0.f;
    const float* qp = &Qs[i][h * DH_];
    const u16* kp = &Ks[j][h * DH_];
#pragma unroll 8
    for (int d = 0; d < DH_; ++d) sum += qp[d] * bf2f(kp[d]);
    P[h][i][j] = sum;
  }
  __syncthreads();
  if (lane < 5) {
    int i = lane;
    float m = P[h][i][0];
#pragma unroll
    for (int j = 1; j < 5; ++j) m = fmaxf(m, P[h][i][j]);
    float e[5], ssum = 0.f;
#pragma unroll
    for (int j = 0; j < 5; ++j) { e[j] = __expf(P[h][i][j] - m); ssum += e[j]; }
    float inv = 1.0f / ssum;
#pragma unroll
    for (int j = 0; j < 5; ++j) P[h][i][j] = e[j] * inv;
  }
  __syncthreads();
  for (int idx = lane; idx < 5 * DH_; idx += 64) {
    int i = idx >> 7, d = idx & (DH_ - 1);
    float o = 0.f;
#pragma unroll
    for (int j = 0; j < 5; ++j) o += P[h][i][j] * bf2f(Vs[j][h * DH_ + d]);
    O[((size_t)b * TOT_ + rows[i]) * D_ + h * DH_ + d] = f2bf(o);
  }
}

// ---------------------------------------------------------------------------
// mean over the 1024 u rows -> (B, D), single kernel (grid 16).
// ---------------------------------------------------------------------------
__global__ __launch_bounds__(256)
void mean_k(const float* __restrict__ X, float* __restrict__ out) {
  int b = blockIdx.x >> 1;
  int d = (blockIdx.x & 1) * 256 + threadIdx.x;
  const float* base = X + ((size_t)b * TOT_ + R_) * D_ + d;
  float a0 = 0.f, a1 = 0.f, a2 = 0.f, a3 = 0.f;
  for (int j = 0; j < U_; j += 4) {
    a0 += base[(size_t)(j + 0) * D_];
    a1 += base[(size_t)(j + 1) * D_];
    a2 += base[(size_t)(j + 2) * D_];
    a3 += base[(size_t)(j + 3) * D_];
  }
  out[b * D_ + d] = (a0 + a1 + a2 + a3) * (1.0f / U_);
}

// ---------------------------------------------------------------------------
// Launch. Workspace layout (byte offsets):
//   X      @ 0          fp32 20,971,520
//   LNbuf  @ 20971520   bf16 10,485,760
//   QKV    @ 31457280   bf16 31,457,280
//   ATT    @ 62914560   bf16 10,485,760
//   WQKVb  @ 86638592   bf16  6,291,456
//   Wob    @ 92930048   bf16  2,097,152
//   W1b    @ 95027200   bf16    524,288
//   W2b    @ 95551488   bf16    524,288
//   bQKV   @ 96075776   fp32     24,576
// ---------------------------------------------------------------------------
extern "C" void kernel_launch(void* const* d_in, const int* in_sizes, int n_in,
                              void* d_out, int out_size, void* d_ws, size_t ws_size,
                              hipStream_t stream) {
  const float* x      = (const float*)d_in[0];
  const float* Wq     = (const float*)d_in[1];
  const float* bq     = (const float*)d_in[2];
  const float* Wkv    = (const float*)d_in[3];
  const float* bkv    = (const float*)d_in[4];
  const float* Wo     = (const float*)d_in[5];
  const float* bo     = (const float*)d_in[6];
  const float* W1     = (const float*)d_in[7];
  const float* b1     = (const float*)d_in[8];
  const float* W2     = (const float*)d_in[9];
  const float* b2     = (const float*)d_in[10];
  const float* ln_in_g  = (const float*)d_in[11];
  const float* ln_in_b  = (const float*)d_in[12];
  const float* ff_ln_g  = (const float*)d_in[13];
  const float* ff_ln_b  = (const float*)d_in[14];
  const float* ln_out_g = (const float*)d_in[15];
  const float* ln_out_b = (const float*)d_in[16];
  float* out = (float*)d_out;

  char* wsb = (char*)d_ws;
  float* X     = (float*)wsb;
  u16*   LNbuf = (u16*)(wsb + 20971520);
  u16*   QKV   = (u16*)(wsb + 31457280);
  u16*   ATT   = (u16*)(wsb + 62914560);
  u16*   WQKVb = (u16*)(wsb + 86638592);
  u16*   Wob   = (u16*)(wsb + 92930048);
  u16*   W1b   = (u16*)(wsb + 95027200);
  u16*   W2b   = (u16*)(wsb + 95551488);
  float* bQKV  = (float*)(wsb + 96075776);

  // merged setup: weight cvt/pack + gather+LN-in(0)
  cvt_gather_k<<<SETUP_GRID, 256, 0, stream>>>(Wq, Wkv, Wo, W1, W2, bq, bkv,
                                               WQKVb, Wob, W1b, W2b, bQKV,
                                               x, ln_in_g, ln_in_b, X, LNbuf);

  for (int l = 0; l < L_; ++l) {
    const u16* WQKV_l = WQKVb + (size_t)l * CH_ * D_;
    const u16* Wo_l   = Wob   + (size_t)l * D_ * D_;
    const u16* W1_l   = W1b   + (size_t)l * FFN_ * D_;
    const u16* W2_l   = W2b   + (size_t)l * D_ * FFN_;
    const float* bQKV_l = bQKV + (size_t)l * CH_;
    const float* bo_l = bo + (size_t)l * D_;
    const float* b1_l = b1 + (size_t)l * FFN_;
    const float* b2_l = b2 + (size_t)l * D_;

    // QKV = LNbuf @ WQKV^T + bQKV  (Q pre-scaled)
    gemm_qkv<<<960, 256, 0, stream>>>(LNbuf, WQKV_l, bQKV_l, QKV);

    // attention -> ATT
    attn_k<<<B_ * NSEG_, 256, 0, stream>>>(QKV, ATT);

    // X += ATT @ Wo^T + bo
    gemm_oproj<<<320, 256, 0, stream>>>(ATT, Wo_l, bo_l, X);

    // fused FFN: LN_ff -> FFN1(relu) -> FFN2 + X + LN_out (+LN_in next)
    if (l < L_ - 1) {
      ffn_fused<1><<<M_ / 16, 256, 0, stream>>>(
          X, ff_ln_g + l * D_, ff_ln_b + l * D_,
          W1_l, b1_l, W2_l, b2_l,
          ln_out_g + l * D_, ln_out_b + l * D_,
          ln_in_g + (l + 1) * D_, ln_in_b + (l + 1) * D_,
          X, LNbuf);
    } else {
      ffn_fused<2><<<M_ / 16, 256, 0, stream>>>(
          X, ff_ln_g + l * D_, ff_ln_b + l * D_,
          W1_l, b1_l, W2_l, b2_l,
          ln_out_g + l * D_, ln_out_b + l * D_,
          nullptr, nullptr,
          X, nullptr);
    }
  }

  mean_k<<<16, 256, 0, stream>>>(X, out);
}

// Round 14
// 380.973 us; speedup vs baseline: 1.0736x; 1.0736x over previous
//
#include <hip/hip_runtime.h>
#include <cstdint>
#include <cstddef>

// Problem constants
#define D_    512
#define H_    4
#define DH_   128
#define FFN_  128
#define L_    4
#define B_    8
#define T_    1025
#define U_    1024
#define NSEG_ 256
#define R_    256
#define TOT_  1280            // R + U
#define M_    (B_*TOT_)       // 10240 rows
#define CH_   1536            // QKV channels

typedef __attribute__((ext_vector_type(8))) short bf16x8;
typedef __attribute__((ext_vector_type(4))) float f32x4;
typedef unsigned short u16;

__device__ __forceinline__ u16 f2bf(float f) {
  unsigned u = __builtin_bit_cast(unsigned, f);
  u += 0x7fff + ((u >> 16) & 1);           // round-to-nearest-even
  return (u16)(u >> 16);
}
__device__ __forceinline__ float bf2f(u16 h) {
  unsigned u = ((unsigned)h) << 16;
  return __builtin_bit_cast(float, u);
}

__device__ __forceinline__ void gload_lds16(const void* g, void* l) {
  __builtin_amdgcn_global_load_lds(
      (const __attribute__((address_space(1))) unsigned*)g,
      (__attribute__((address_space(3))) unsigned*)l, 16, 0, 0);
}

#define QSCALE 0.08838834764831845f   // 128^-0.5, folded into Wq/bq

#define CVT_BLOCKS 4614
#define SETUP_GRID (CVT_BLOCKS + M_)   // 4614 cvt blocks + 10240 gather rows

// ---------------------------------------------------------------------------
// merged one-shot setup: weight cvt/pack (blocks 0..4613) + gather+LN-in(0)
// (blocks 4614..14853). Wq/bq are pre-scaled by QSCALE so attention skips it.
// ---------------------------------------------------------------------------
__global__ __launch_bounds__(256)
void cvt_gather_k(const float* __restrict__ Wq, const float* __restrict__ Wkv,
                  const float* __restrict__ Wo, const float* __restrict__ W1,
                  const float* __restrict__ W2, const float* __restrict__ bq,
                  const float* __restrict__ bkv,
                  u16* __restrict__ WQKVb, u16* __restrict__ Wob,
                  u16* __restrict__ W1b, u16* __restrict__ W2b,
                  float* __restrict__ bQKV,
                  const float* __restrict__ x, const float* __restrict__ g,
                  const float* __restrict__ bb, float* __restrict__ X,
                  u16* __restrict__ LNb) {
  __shared__ float red[10];
  const int bid = blockIdx.x;
  const int tid = threadIdx.x;

  if (bid >= CVT_BLOCKS) {
    // ---- gather + LN-in(layer 0) ----
    int row = bid - CVT_BLOCKS;
    int b = row / TOT_, p = row % TOT_;
    int t = (p < R_) ? ((p < R_ - 1) ? 4 * (p + 1) : (T_ - 1)) : (p - R_);
    const float* xr = x + ((size_t)b * T_ + t) * D_;
    float e0 = xr[tid], e1 = xr[tid + 256];
    X[(size_t)row * D_ + tid] = e0;
    X[(size_t)row * D_ + tid + 256] = e1;
    float s = e0 + e1, ss = e0 * e0 + e1 * e1;
#pragma unroll
    for (int off = 32; off > 0; off >>= 1) {
      s  += __shfl_down(s, off);
      ss += __shfl_down(ss, off);
    }
    int wid = tid >> 6, lane = tid & 63;
    if (lane == 0) { red[wid] = s; red[4 + wid] = ss; }
    __syncthreads();
    if (tid == 0) {
      float S = red[0] + red[1] + red[2] + red[3];
      float SS = red[4] + red[5] + red[6] + red[7];
      float mu = S * (1.0f / D_);
      float var = SS * (1.0f / D_) - mu * mu;
      if (var < 0.f) var = 0.f;
      red[8] = mu; red[9] = rsqrtf(var + 1e-5f);
    }
    __syncthreads();
    float mu = red[8], rs = red[9];
    u16* yr = LNb + (size_t)row * D_;
    yr[tid]       = f2bf((e0 - mu) * rs * g[tid]       + bb[tid]);
    yr[tid + 256] = f2bf((e1 - mu) * rs * g[tid + 256] + bb[tid + 256]);
    return;
  }

  // ---- weight conversion / packing ----
  int i4 = bid * 256 + tid;
  if (i4 < 786432) {                        // WQKV: 3,145,728 elems
    int e = i4 * 4;
    int l = e / 786432;
    int rem = e - l * 786432;
    int n = rem >> 9, k = rem & 511;
    const float* src = (n < 512) ? (Wq + (size_t)l * 262144 + n * 512 + k)
                                 : (Wkv + (size_t)l * 524288 + (n - 512) * 512 + k);
    float4 v = *(const float4*)src;
    if (n < 512) { v.x *= QSCALE; v.y *= QSCALE; v.z *= QSCALE; v.w *= QSCALE; }
    ushort4 o; o.x = f2bf(v.x); o.y = f2bf(v.y); o.z = f2bf(v.z); o.w = f2bf(v.w);
    *(ushort4*)(WQKVb + e) = o;
  } else if (i4 < 1048576) {                // Wo
    int e = (i4 - 786432) * 4;
    float4 v = *(const float4*)(Wo + e);
    ushort4 o; o.x = f2bf(v.x); o.y = f2bf(v.y); o.z = f2bf(v.z); o.w = f2bf(v.w);
    *(ushort4*)(Wob + e) = o;
  } else if (i4 < 1114112) {                // W1
    int e = (i4 - 1048576) * 4;
    float4 v = *(const float4*)(W1 + e);
    ushort4 o; o.x = f2bf(v.x); o.y = f2bf(v.y); o.z = f2bf(v.z); o.w = f2bf(v.w);
    *(ushort4*)(W1b + e) = o;
  } else if (i4 < 1179648) {                // W2
    int e = (i4 - 1114112) * 4;
    float4 v = *(const float4*)(W2 + e);
    ushort4 o; o.x = f2bf(v.x); o.y = f2bf(v.y); o.z = f2bf(v.z); o.w = f2bf(v.w);
    *(ushort4*)(W2b + e) = o;
  } else if (i4 < 1181184) {                // bias: 6144 elems
    int e = (i4 - 1179648) * 4;
    int l = e / 1536, n = e - l * 1536;
#pragma unroll
    for (int t = 0; t < 4; ++t) {
      int nn = n + t;
      bQKV[e + t] = (nn < 512) ? bq[l * 512 + nn] * QSCALE
                               : bkv[l * 1024 + (nn - 512)];
    }
  }
}

// ---------------------------------------------------------------------------
// bf16 MFMA GEMM, m97-style (128x128 tile, BK=32, 4 waves), XCD-swizzled.
// QKV projection: M=10240, N=1536, K=512. xcd=bid&7 owns 10 row-stripes
// x 12 col-blocks -> A chunk 1.28MB L2-resident per XCD.
// ---------------------------------------------------------------------------
#define GBK 32

__global__ __launch_bounds__(256)
void gemm_qkv(const u16* __restrict__ A, const u16* __restrict__ Bw,
              const float* __restrict__ bias, u16* __restrict__ Cout) {
  __shared__ __align__(16) u16 As[128 * GBK];
  __shared__ __align__(16) u16 Bs[128 * GBK];
  const int tid = threadIdx.x;
  const int wid = tid >> 6;
  const int lane = tid & 63;
  const int bid = blockIdx.x;
  const int xcd = bid & 7;
  const int t = bid >> 3;                 // 0..119
  const int cb = t % 12;
  const int rb = xcd * 10 + t / 12;
  const int bm = rb * 128;
  const int bn = cb * 128;
  const int wr = wid >> 1, wc = wid & 1;

  const int srow = tid >> 2;
  const int skoff = (tid & 3) << 3;

  f32x4 acc[4][4] = {};

  const u16* Ag0 = A  + (size_t)(bm + srow)      * D_ + skoff;
  const u16* Ag1 = A  + (size_t)(bm + 64 + srow) * D_ + skoff;
  const u16* Bg0 = Bw + (size_t)(bn + srow)      * D_ + skoff;
  const u16* Bg1 = Bw + (size_t)(bn + 64 + srow) * D_ + skoff;
  u16* AsW0 = &As[(size_t)(wid * 16)      * GBK];
  u16* AsW1 = &As[(size_t)(64 + wid * 16) * GBK];
  u16* BsW0 = &Bs[(size_t)(wid * 16)      * GBK];
  u16* BsW1 = &Bs[(size_t)(64 + wid * 16) * GBK];

  const int lrow = lane & 15;
  const int lko  = (lane >> 4) * 16;

  for (int k0 = 0; k0 < D_; k0 += GBK) {
    __syncthreads();
    gload_lds16(Ag0 + k0, AsW0);
    gload_lds16(Ag1 + k0, AsW1);
    gload_lds16(Bg0 + k0, BsW0);
    gload_lds16(Bg1 + k0, BsW1);
    __syncthreads();

    bf16x8 afrag[4], bfrag[4];
#pragma unroll
    for (int m = 0; m < 4; ++m) {
      int row = wr * 64 + m * 16 + lrow;
      afrag[m] = *(const bf16x8*)((const char*)As + row * (GBK * 2) + lko);
    }
#pragma unroll
    for (int n = 0; n < 4; ++n) {
      int col = wc * 64 + n * 16 + lrow;
      bfrag[n] = *(const bf16x8*)((const char*)Bs + col * (GBK * 2) + lko);
    }
#pragma unroll
    for (int m = 0; m < 4; ++m)
#pragma unroll
      for (int n = 0; n < 4; ++n)
        acc[m][n] = __builtin_amdgcn_mfma_f32_16x16x32_bf16(
            afrag[m], bfrag[n], acc[m][n], 0, 0, 0);
  }

  const int lcol  = lane & 15;
  const int lrow4 = (lane >> 4) * 4;
#pragma unroll
  for (int m = 0; m < 4; ++m) {
    int rowbase = bm + wr * 64 + m * 16 + lrow4;
#pragma unroll
    for (int n = 0; n < 4; ++n) {
      int col = bn + wc * 64 + n * 16 + lcol;
      float bv = bias[col];
#pragma unroll
      for (int j = 0; j < 4; ++j) {
        int row = rowbase + j;
        Cout[(size_t)row * CH_ + col] = f2bf(acc[m][n][j] + bv);
      }
    }
  }
}

// ---------------------------------------------------------------------------
// O-proj: pure N-tiled GEMM + residual, fp32 out (in-place X).
// 128x128 tile, 4 waves, grid 320 = 8 xcd x 4 cb x 10 rb.
// ---------------------------------------------------------------------------
__global__ __launch_bounds__(256)
void gemm_oproj(const u16* __restrict__ A, const u16* __restrict__ Bw,
                const float* __restrict__ bias, float* __restrict__ Xio) {
  __shared__ __align__(16) u16 As[128 * GBK];
  __shared__ __align__(16) u16 Bs[128 * GBK];
  const int tid = threadIdx.x;
  const int wid = tid >> 6;
  const int lane = tid & 63;
  const int bid = blockIdx.x;
  const int xcd = bid & 7;
  const int t = bid >> 3;                 // 0..39
  const int cb = t & 3;
  const int rb = xcd * 10 + (t >> 2);
  const int bm = rb * 128;
  const int bn = cb * 128;
  const int wr = wid >> 1, wc = wid & 1;

  const int srow = tid >> 2;
  const int skoff = (tid & 3) << 3;

  f32x4 acc[4][4] = {};

  const u16* Ag0 = A  + (size_t)(bm + srow)      * D_ + skoff;
  const u16* Ag1 = A  + (size_t)(bm + 64 + srow) * D_ + skoff;
  const u16* Bg0 = Bw + (size_t)(bn + srow)      * D_ + skoff;
  const u16* Bg1 = Bw + (size_t)(bn + 64 + srow) * D_ + skoff;
  u16* AsW0 = &As[(size_t)(wid * 16)      * GBK];
  u16* AsW1 = &As[(size_t)(64 + wid * 16) * GBK];
  u16* BsW0 = &Bs[(size_t)(wid * 16)      * GBK];
  u16* BsW1 = &Bs[(size_t)(64 + wid * 16) * GBK];

  const int lrow = lane & 15;
  const int lko  = (lane >> 4) * 16;

  for (int k0 = 0; k0 < D_; k0 += GBK) {
    __syncthreads();
    gload_lds16(Ag0 + k0, AsW0);
    gload_lds16(Ag1 + k0, AsW1);
    gload_lds16(Bg0 + k0, BsW0);
    gload_lds16(Bg1 + k0, BsW1);
    __syncthreads();

    bf16x8 afrag[4], bfrag[4];
#pragma unroll
    for (int m = 0; m < 4; ++m) {
      int row = wr * 64 + m * 16 + lrow;
      afrag[m] = *(const bf16x8*)((const char*)As + row * (GBK * 2) + lko);
    }
#pragma unroll
    for (int n = 0; n < 4; ++n) {
      int col = wc * 64 + n * 16 + lrow;
      bfrag[n] = *(const bf16x8*)((const char*)Bs + col * (GBK * 2) + lko);
    }
#pragma unroll
    for (int m = 0; m < 4; ++m)
#pragma unroll
      for (int n = 0; n < 4; ++n)
        acc[m][n] = __builtin_amdgcn_mfma_f32_16x16x32_bf16(
            afrag[m], bfrag[n], acc[m][n], 0, 0, 0);
  }

  const int lcol  = lane & 15;
  const int lrow4 = (lane >> 4) * 4;
#pragma unroll
  for (int m = 0; m < 4; ++m) {
    int rowbase = bm + wr * 64 + m * 16 + lrow4;
#pragma unroll
    for (int n = 0; n < 4; ++n) {
      int col = bn + wc * 64 + n * 16 + lcol;
      float bv = bias[col];
#pragma unroll
      for (int j = 0; j < 4; ++j) {
        size_t idx = (size_t)(rowbase + j) * D_ + col;
        Xio[idx] = acc[m][n][j] + bv + Xio[idx];
      }
    }
  }
}

// ---------------------------------------------------------------------------
// Fused FFN: LN_ff (register prologue) -> FFN1(relu, H in regs->LDS) ->
// FFN2 + residual + LN_out (+ LN_in next). 16-row tiles, grid 640.
// MODE 1 (l<3): LN1 -> Xout fp32; LN2 -> OutBf bf16.   MODE 2: LN1 only.
// ---------------------------------------------------------------------------
template <int MODE>
__global__ __launch_bounds__(256)
void ffn_fused(const float* __restrict__ X,
               const float* __restrict__ gff, const float* __restrict__ bff,
               const u16* __restrict__ W1, const float* __restrict__ b1,
               const u16* __restrict__ W2, const float* __restrict__ b2,
               const float* __restrict__ g1, const float* __restrict__ b1o,
               const float* __restrict__ g2, const float* __restrict__ b2i,
               float* __restrict__ Xout, u16* __restrict__ OutBf) {
  __shared__ __align__(16) u16 Bs[512 * 32];    // 32KB: W1 (first 8KB) / W2
  __shared__ __align__(16) u16 Aln[16 * 512];   // 16KB swizzled; Hs overlays
  __shared__ float wsum[4][16], wss[4][16], mu_s[16], rs_s[16];
  u16* Hs = Aln;                                // 4KB overlay (post phase A)
  const int tid = threadIdx.x;
  const int wid = tid >> 6, lane = tid & 63;
  const int bm = blockIdx.x * 16;
  const int r  = tid >> 4;            // 0..15 row in tile
  const int jj = tid & 15;            // 16 lanes per row

  // ---- LN_ff prologue (in registers) ----
  {
    const float* xr = X + (size_t)(bm + r) * D_ + jj * 32;
    float v[32];
    float s = 0.f, ss = 0.f;
#pragma unroll
    for (int i = 0; i < 8; ++i) {
      float4 q = *(const float4*)(xr + i * 4);
      v[i * 4 + 0] = q.x; v[i * 4 + 1] = q.y;
      v[i * 4 + 2] = q.z; v[i * 4 + 3] = q.w;
      s  += q.x + q.y + q.z + q.w;
      ss += q.x * q.x + q.y * q.y + q.z * q.z + q.w * q.w;
    }
#pragma unroll
    for (int off = 1; off < 16; off <<= 1) {
      s  += __shfl_xor(s, off);
      ss += __shfl_xor(ss, off);
    }
    float mu = s * (1.0f / D_);
    float var = ss * (1.0f / D_) - mu * mu;
    if (var < 0.f) var = 0.f;
    float rs = rsqrtf(var + 1e-5f);
    char* Ab = (char*)Aln;
#pragma unroll
    for (int i = 0; i < 8; ++i) {
      int c0 = jj * 32 + i * 4;
      float4 g4 = *(const float4*)(gff + c0);
      float4 b4 = *(const float4*)(bff + c0);
      ushort4 o;
      o.x = f2bf((v[i * 4 + 0] - mu) * rs * g4.x + b4.x);
      o.y = f2bf((v[i * 4 + 1] - mu) * rs * g4.y + b4.y);
      o.z = f2bf((v[i * 4 + 2] - mu) * rs * g4.z + b4.z);
      o.w = f2bf((v[i * 4 + 3] - mu) * rs * g4.w + b4.w);
      int byteoff = (r * 1024 + c0 * 2) ^ ((r & 7) << 4);
      *(ushort4*)(Ab + byteoff) = o;
    }
  }
  __syncthreads();

  // ---- phase A: H = relu(LN_ff @ W1^T + b1), H in registers ----
  const int lrow = lane & 15;
  const int lko  = (lane >> 4) << 4;   // bytes
  const int l4 = lane >> 2;
  const int k8 = (lane & 3) << 3;
  f32x4 accA[2] = {};

  for (int k0 = 0; k0 < D_; k0 += 32) {
    if (k0) __syncthreads();
#pragma unroll
    for (int p = 0; p < 2; ++p) {
      int rowb = wid * 32 + p * 16 + l4;
      gload_lds16(W1 + (size_t)rowb * D_ + k0 + k8,
                  (char*)Bs + (wid * 32 + p * 16) * 64);
    }
    __syncthreads();
    bf16x8 af = *(const bf16x8*)((const char*)Aln +
                  ((lrow * 1024 + k0 * 2 + lko) ^ ((lrow & 7) << 4)));
    bf16x8 bf[2];
#pragma unroll
    for (int n = 0; n < 2; ++n)
      bf[n] = *(const bf16x8*)((const char*)Bs + (wid * 32 + n * 16 + lrow) * 64 + lko);
#pragma unroll
    for (int n = 0; n < 2; ++n)
      accA[n] = __builtin_amdgcn_mfma_f32_16x16x32_bf16(af, bf[n], accA[n], 0, 0, 0);
  }

  const int lcol = lane & 15;
  const int lr4 = (lane >> 4) * 4;
  __syncthreads();                     // all Aln/Bs reads complete

  // ---- hand H to LDS (bias + relu, swizzled; overlays Aln) ----
#pragma unroll
  for (int n = 0; n < 2; ++n) {
    int col = wid * 32 + n * 16 + lcol;
    float bv = b1[col];
#pragma unroll
    for (int j = 0; j < 4; ++j) {
      int rr = lr4 + j;
      float hv = fmaxf(accA[n][j] + bv, 0.f);
      int byteoff = (rr * 256 + col * 2) ^ ((rr & 7) << 4);
      *(u16*)((char*)Hs + byteoff) = f2bf(hv);
    }
  }

  // ---- phase B: FFN2 + residual + LN_out (+ LN_in) ----
  f32x4 acc[8] = {};
  for (int k0 = 0; k0 < FFN_; k0 += 32) {
    __syncthreads();                   // k0=0: Hs visible; else: reads done
#pragma unroll
    for (int p = 0; p < 8; ++p) {
      int row = wid * 128 + p * 16 + l4;
      gload_lds16(W2 + (size_t)row * FFN_ + k0 + k8,
                  (char*)Bs + (wid * 128 + p * 16) * 64);
    }
    __syncthreads();

    bf16x8 af = *(const bf16x8*)((const char*)Hs +
                  ((lrow * 256 + k0 * 2 + lko) ^ ((lrow & 7) << 4)));
    bf16x8 bf[8];
#pragma unroll
    for (int n = 0; n < 8; ++n)
      bf[n] = *(const bf16x8*)((const char*)Bs + (wid * 128 + n * 16 + lrow) * 64 + lko);
#pragma unroll
    for (int n = 0; n < 8; ++n)
      acc[n] = __builtin_amdgcn_mfma_f32_16x16x32_bf16(af, bf[n], acc[n], 0, 0, 0);
  }

  // ---- bias + residual ----
#pragma unroll
  for (int n = 0; n < 8; ++n) {
    int col = wid * 128 + n * 16 + lcol;
    float bv = b2[col];
#pragma unroll
    for (int j = 0; j < 4; ++j) {
      int row = bm + lr4 + j;
      acc[n][j] = acc[n][j] + bv + X[(size_t)row * D_ + col];
    }
  }

  // ---- LN pass 1 (ln_out) ----
  {
    float s0[4] = {}, s1[4] = {};
#pragma unroll
    for (int n = 0; n < 8; ++n)
#pragma unroll
      for (int j = 0; j < 4; ++j) {
        float v = acc[n][j];
        s0[j] += v; s1[j] += v * v;
      }
#pragma unroll
    for (int off = 1; off < 16; off <<= 1)
#pragma unroll
      for (int j = 0; j < 4; ++j) {
        s0[j] += __shfl_xor(s0[j], off);
        s1[j] += __shfl_xor(s1[j], off);
      }
    if ((lane & 15) == 0) {
#pragma unroll
      for (int j = 0; j < 4; ++j) {
        wsum[wid][lr4 + j] = s0[j]; wss[wid][lr4 + j] = s1[j];
      }
    }
  }
  __syncthreads();
  if (tid < 16) {
    float S  = wsum[0][tid] + wsum[1][tid] + wsum[2][tid] + wsum[3][tid];
    float SS = wss[0][tid] + wss[1][tid] + wss[2][tid] + wss[3][tid];
    float mu = S * (1.0f / D_);
    float var = SS * (1.0f / D_) - mu * mu;
    if (var < 0.f) var = 0.f;
    mu_s[tid] = mu; rs_s[tid] = rsqrtf(var + 1e-5f);
  }
  __syncthreads();

  float gg[8], bv2[8];
#pragma unroll
  for (int n = 0; n < 8; ++n) {
    int col = wid * 128 + n * 16 + lcol;
    gg[n] = g1[col]; bv2[n] = b1o[col];
  }
#pragma unroll
  for (int n = 0; n < 8; ++n) {
    int col = wid * 128 + n * 16 + lcol;
#pragma unroll
    for (int j = 0; j < 4; ++j) {
      int rr = lr4 + j;
      int row = bm + rr;
      float ln = (acc[n][j] - mu_s[rr]) * rs_s[rr] * gg[n] + bv2[n];
      Xout[(size_t)row * D_ + col] = ln;
      acc[n][j] = ln;
    }
  }

  if (MODE == 1) {
    // ---- LN pass 2 (ln_in next layer) ----
    __syncthreads();
    {
      float s0[4] = {}, s1[4] = {};
#pragma unroll
      for (int n = 0; n < 8; ++n)
#pragma unroll
        for (int j = 0; j < 4; ++j) {
          float v = acc[n][j];
          s0[j] += v; s1[j] += v * v;
        }
#pragma unroll
      for (int off = 1; off < 16; off <<= 1)
#pragma unroll
        for (int j = 0; j < 4; ++j) {
          s0[j] += __shfl_xor(s0[j], off);
          s1[j] += __shfl_xor(s1[j], off);
        }
      if ((lane & 15) == 0) {
#pragma unroll
        for (int j = 0; j < 4; ++j) {
          wsum[wid][lr4 + j] = s0[j]; wss[wid][lr4 + j] = s1[j];
        }
      }
    }
    __syncthreads();
    if (tid < 16) {
      float S  = wsum[0][tid] + wsum[1][tid] + wsum[2][tid] + wsum[3][tid];
      float SS = wss[0][tid] + wss[1][tid] + wss[2][tid] + wss[3][tid];
      float mu = S * (1.0f / D_);
      float var = SS * (1.0f / D_) - mu * mu;
      if (var < 0.f) var = 0.f;
      mu_s[tid] = mu; rs_s[tid] = rsqrtf(var + 1e-5f);
    }
    __syncthreads();
#pragma unroll
    for (int n = 0; n < 8; ++n) {
      int col = wid * 128 + n * 16 + lcol;
      gg[n] = g2[col]; bv2[n] = b2i[col];
    }
#pragma unroll
    for (int n = 0; n < 8; ++n) {
      int col = wid * 128 + n * 16 + lcol;
#pragma unroll
      for (int j = 0; j < 4; ++j) {
        int rr = lr4 + j;
        int row = bm + rr;
        float ln = (acc[n][j] - mu_s[rr]) * rs_s[rr] * gg[n] + bv2[n];
        OutBf[(size_t)row * D_ + col] = f2bf(ln);
      }
    }
  }
}

// ---------------------------------------------------------------------------
// Block-diagonal attention reading fused QKV (stride 1536), f32 LDS,
// vectorized loads. Scale pre-folded into Wq/bq. One block per (b, seg);
// wave h = head h. Segment rows: {s, 256+4s..+3}.
// ---------------------------------------------------------------------------
#define QLD 516
__global__ __launch_bounds__(256)
void attn_k(const u16* __restrict__ QKV, u16* __restrict__ O) {
  int bs = blockIdx.x;
  int b = bs >> 8, s = bs & 255;
  __shared__ float Qs[5][QLD];
  __shared__ float Ks[5][QLD];
  __shared__ float Vs[5][QLD];
  __shared__ float P[H_][5][5];
  int tid = threadIdx.x;
  int rows[5];
  rows[0] = s;
#pragma unroll
  for (int i = 1; i < 5; ++i) rows[i] = R_ + 4 * s + (i - 1);
  // 960 chunks of 8 bf16: mtx (Q/K/V) x 5 rows x 64 chunks
  for (int idx = tid; idx < 960; idx += 256) {
    int mtx = idx / 320;
    int rem = idx - mtx * 320;
    int i = rem >> 6, c8 = rem & 63;
    size_t base = ((size_t)b * TOT_ + rows[i]) * CH_ + mtx * 512 + c8 * 8;
    bf16x8 v = *(const bf16x8*)(QKV + base);
    float* dst = (mtx == 0) ? &Qs[i][c8 * 8] : (mtx == 1 ? &Ks[i][c8 * 8] : &Vs[i][c8 * 8]);
#pragma unroll
    for (int t = 0; t < 8; ++t) dst[t] = bf2f((u16)v[t]);
  }
  __syncthreads();
  int h = tid >> 6, lane = tid & 63;
  if (lane < 25) {
    int i = lane / 5, j = lane % 5;
    float sum = 0.f;
    const float* qp = &Qs[i][h * DH_];
    const float* kp = &Ks[j][h * DH_];
#pragma unroll 8
    for (int d = 0; d < DH_; ++d) sum += qp[d] * kp[d];
    P[h][i][j] = sum;
  }
  __syncthreads();
  if (lane < 5) {
    int i = lane;
    float m = P[h][i][0];
#pragma unroll
    for (int j = 1; j < 5; ++j) m = fmaxf(m, P[h][i][j]);
    float e[5], ssum = 0.f;
#pragma unroll
    for (int j = 0; j < 5; ++j) { e[j] = __expf(P[h][i][j] - m); ssum += e[j]; }
    float inv = 1.0f / ssum;
#pragma unroll
    for (int j = 0; j < 5; ++j) P[h][i][j] = e[j] * inv;
  }
  __syncthreads();
  for (int idx = lane; idx < 5 * DH_; idx += 64) {
    int i = idx >> 7, d = idx & (DH_ - 1);
    float o = 0.f;
#pragma unroll
    for (int j = 0; j < 5; ++j) o += P[h][i][j] * Vs[j][h * DH_ + d];
    O[((size_t)b * TOT_ + rows[i]) * D_ + h * DH_ + d] = f2bf(o);
  }
}

// ---------------------------------------------------------------------------
// mean over the 1024 u rows -> (B, D), two stages (128 + 16 blocks).
// ---------------------------------------------------------------------------
__global__ __launch_bounds__(256)
void mean_part_k(const float* __restrict__ X, float* __restrict__ part) {
  int d = blockIdx.x * 256 + threadIdx.x;
  int jc = blockIdx.y;
  int b = blockIdx.z;
  float acc = 0.f;
  const float* base = X + ((size_t)b * TOT_ + R_ + jc * 128) * D_ + d;
  for (int j = 0; j < 128; ++j) acc += base[(size_t)j * D_];
  part[((size_t)b * 8 + jc) * D_ + d] = acc;
}

__global__ __launch_bounds__(256)
void mean_final_k(const float* __restrict__ part, float* __restrict__ out) {
  int i = blockIdx.x * 256 + threadIdx.x;
  int b = i >> 9, d = i & (D_ - 1);
  float acc = 0.f;
#pragma unroll
  for (int c = 0; c < 8; ++c) acc += part[((size_t)b * 8 + c) * D_ + d];
  out[i] = acc * (1.0f / U_);
}

// ---------------------------------------------------------------------------
// Launch. Workspace layout (byte offsets):
//   X      @ 0          fp32 20,971,520
//   LNbuf  @ 20971520   bf16 10,485,760
//   QKV    @ 31457280   bf16 31,457,280
//   ATT    @ 62914560   bf16 10,485,760
//   part   @ 86507520   fp32    131,072
//   WQKVb  @ 86638592   bf16  6,291,456
//   Wob    @ 92930048   bf16  2,097,152
//   W1b    @ 95027200   bf16    524,288
//   W2b    @ 95551488   bf16    524,288
//   bQKV   @ 96075776   fp32     24,576
// ---------------------------------------------------------------------------
extern "C" void kernel_launch(void* const* d_in, const int* in_sizes, int n_in,
                              void* d_out, int out_size, void* d_ws, size_t ws_size,
                              hipStream_t stream) {
  const float* x      = (const float*)d_in[0];
  const float* Wq     = (const float*)d_in[1];
  const float* bq     = (const float*)d_in[2];
  const float* Wkv    = (const float*)d_in[3];
  const float* bkv    = (const float*)d_in[4];
  const float* Wo     = (const float*)d_in[5];
  const float* bo     = (const float*)d_in[6];
  const float* W1     = (const float*)d_in[7];
  const float* b1     = (const float*)d_in[8];
  const float* W2     = (const float*)d_in[9];
  const float* b2     = (const float*)d_in[10];
  const float* ln_in_g  = (const float*)d_in[11];
  const float* ln_in_b  = (const float*)d_in[12];
  const float* ff_ln_g  = (const float*)d_in[13];
  const float* ff_ln_b  = (const float*)d_in[14];
  const float* ln_out_g = (const float*)d_in[15];
  const float* ln_out_b = (const float*)d_in[16];
  float* out = (float*)d_out;

  char* wsb = (char*)d_ws;
  float* X     = (float*)wsb;
  u16*   LNbuf = (u16*)(wsb + 20971520);
  u16*   QKV   = (u16*)(wsb + 31457280);
  u16*   ATT   = (u16*)(wsb + 62914560);
  float* part  = (float*)(wsb + 86507520);
  u16*   WQKVb = (u16*)(wsb + 86638592);
  u16*   Wob   = (u16*)(wsb + 92930048);
  u16*   W1b   = (u16*)(wsb + 95027200);
  u16*   W2b   = (u16*)(wsb + 95551488);
  float* bQKV  = (float*)(wsb + 96075776);

  // merged setup: weight cvt/pack + gather+LN-in(0)
  cvt_gather_k<<<SETUP_GRID, 256, 0, stream>>>(Wq, Wkv, Wo, W1, W2, bq, bkv,
                                               WQKVb, Wob, W1b, W2b, bQKV,
                                               x, ln_in_g, ln_in_b, X, LNbuf);

  for (int l = 0; l < L_; ++l) {
    const u16* WQKV_l = WQKVb + (size_t)l * CH_ * D_;
    const u16* Wo_l   = Wob   + (size_t)l * D_ * D_;
    const u16* W1_l   = W1b   + (size_t)l * FFN_ * D_;
    const u16* W2_l   = W2b   + (size_t)l * D_ * FFN_;
    const float* bQKV_l = bQKV + (size_t)l * CH_;
    const float* bo_l = bo + (size_t)l * D_;
    const float* b1_l = b1 + (size_t)l * FFN_;
    const float* b2_l = b2 + (size_t)l * D_;

    // QKV = LNbuf @ WQKV^T + bQKV  (Q pre-scaled)
    gemm_qkv<<<960, 256, 0, stream>>>(LNbuf, WQKV_l, bQKV_l, QKV);

    // attention -> ATT
    attn_k<<<B_ * NSEG_, 256, 0, stream>>>(QKV, ATT);

    // X += ATT @ Wo^T + bo
    gemm_oproj<<<320, 256, 0, stream>>>(ATT, Wo_l, bo_l, X);

    // fused FFN: LN_ff -> FFN1(relu) -> FFN2 + X + LN_out (+LN_in next)
    if (l < L_ - 1) {
      ffn_fused<1><<<M_ / 16, 256, 0, stream>>>(
          X, ff_ln_g + l * D_, ff_ln_b + l * D_,
          W1_l, b1_l, W2_l, b2_l,
          ln_out_g + l * D_, ln_out_b + l * D_,
          ln_in_g + (l + 1) * D_, ln_in_b + (l + 1) * D_,
          X, LNbuf);
    } else {
      ffn_fused<2><<<M_ / 16, 256, 0, stream>>>(
          X, ff_ln_g + l * D_, ff_ln_b + l * D_,
          W1_l, b1_l, W2_l, b2_l,
          ln_out_g + l * D_, ln_out_b + l * D_,
          nullptr, nullptr,
          X, nullptr);
    }
  }

  mean_part_k<<<dim3(2, 8, 8), 256, 0, stream>>>(X, part);
  mean_final_k<<<(B_ * D_) / 256, 256, 0, stream>>>(part, out);
}

// Round 15
// 363.291 us; speedup vs baseline: 1.1259x; 1.0487x over previous
//
#include <hip/hip_runtime.h>
#include <cstdint>
#include <cstddef>

// Problem constants
#define D_    512
#define H_    4
#define DH_   128
#define FFN_  128
#define L_    4
#define B_    8
#define T_    1025
#define U_    1024
#define NSEG_ 256
#define R_    256
#define TOT_  1280            // R + U
#define M_    (B_*TOT_)       // 10240 rows
#define CH_   1536            // QKV channels

typedef __attribute__((ext_vector_type(8))) short bf16x8;
typedef __attribute__((ext_vector_type(4))) float f32x4;
typedef unsigned short u16;

__device__ __forceinline__ u16 f2bf(float f) {
  unsigned u = __builtin_bit_cast(unsigned, f);
  u += 0x7fff + ((u >> 16) & 1);           // round-to-nearest-even
  return (u16)(u >> 16);
}
__device__ __forceinline__ float bf2f(u16 h) {
  unsigned u = ((unsigned)h) << 16;
  return __builtin_bit_cast(float, u);
}

__device__ __forceinline__ void gload_lds16(const void* g, void* l) {
  __builtin_amdgcn_global_load_lds(
      (const __attribute__((address_space(1))) unsigned*)g,
      (__attribute__((address_space(3))) unsigned*)l, 16, 0, 0);
}

#define QSCALE 0.08838834764831845f   // 128^-0.5, folded into Wq/bq

#define CVT_BLOCKS 4614
#define SETUP_GRID (CVT_BLOCKS + M_)   // 4614 cvt blocks + 10240 gather rows

// ---------------------------------------------------------------------------
// merged one-shot setup: weight cvt/pack (blocks 0..4613) + gather+LN-in(0)
// (blocks 4614..14853). Wq/bq are pre-scaled by QSCALE so attention skips it.
// ---------------------------------------------------------------------------
__global__ __launch_bounds__(256)
void cvt_gather_k(const float* __restrict__ Wq, const float* __restrict__ Wkv,
                  const float* __restrict__ Wo, const float* __restrict__ W1,
                  const float* __restrict__ W2, const float* __restrict__ bq,
                  const float* __restrict__ bkv,
                  u16* __restrict__ WQKVb, u16* __restrict__ Wob,
                  u16* __restrict__ W1b, u16* __restrict__ W2b,
                  float* __restrict__ bQKV,
                  const float* __restrict__ x, const float* __restrict__ g,
                  const float* __restrict__ bb, float* __restrict__ X,
                  u16* __restrict__ LNb) {
  __shared__ float red[10];
  const int bid = blockIdx.x;
  const int tid = threadIdx.x;

  if (bid >= CVT_BLOCKS) {
    // ---- gather + LN-in(layer 0) ----
    int row = bid - CVT_BLOCKS;
    int b = row / TOT_, p = row % TOT_;
    int t = (p < R_) ? ((p < R_ - 1) ? 4 * (p + 1) : (T_ - 1)) : (p - R_);
    const float* xr = x + ((size_t)b * T_ + t) * D_;
    float e0 = xr[tid], e1 = xr[tid + 256];
    X[(size_t)row * D_ + tid] = e0;
    X[(size_t)row * D_ + tid + 256] = e1;
    float s = e0 + e1, ss = e0 * e0 + e1 * e1;
#pragma unroll
    for (int off = 32; off > 0; off >>= 1) {
      s  += __shfl_down(s, off);
      ss += __shfl_down(ss, off);
    }
    int wid = tid >> 6, lane = tid & 63;
    if (lane == 0) { red[wid] = s; red[4 + wid] = ss; }
    __syncthreads();
    if (tid == 0) {
      float S = red[0] + red[1] + red[2] + red[3];
      float SS = red[4] + red[5] + red[6] + red[7];
      float mu = S * (1.0f / D_);
      float var = SS * (1.0f / D_) - mu * mu;
      if (var < 0.f) var = 0.f;
      red[8] = mu; red[9] = rsqrtf(var + 1e-5f);
    }
    __syncthreads();
    float mu = red[8], rs = red[9];
    u16* yr = LNb + (size_t)row * D_;
    yr[tid]       = f2bf((e0 - mu) * rs * g[tid]       + bb[tid]);
    yr[tid + 256] = f2bf((e1 - mu) * rs * g[tid + 256] + bb[tid + 256]);
    return;
  }

  // ---- weight conversion / packing ----
  int i4 = bid * 256 + tid;
  if (i4 < 786432) {                        // WQKV: 3,145,728 elems
    int e = i4 * 4;
    int l = e / 786432;
    int rem = e - l * 786432;
    int n = rem >> 9, k = rem & 511;
    const float* src = (n < 512) ? (Wq + (size_t)l * 262144 + n * 512 + k)
                                 : (Wkv + (size_t)l * 524288 + (n - 512) * 512 + k);
    float4 v = *(const float4*)src;
    if (n < 512) { v.x *= QSCALE; v.y *= QSCALE; v.z *= QSCALE; v.w *= QSCALE; }
    ushort4 o; o.x = f2bf(v.x); o.y = f2bf(v.y); o.z = f2bf(v.z); o.w = f2bf(v.w);
    *(ushort4*)(WQKVb + e) = o;
  } else if (i4 < 1048576) {                // Wo
    int e = (i4 - 786432) * 4;
    float4 v = *(const float4*)(Wo + e);
    ushort4 o; o.x = f2bf(v.x); o.y = f2bf(v.y); o.z = f2bf(v.z); o.w = f2bf(v.w);
    *(ushort4*)(Wob + e) = o;
  } else if (i4 < 1114112) {                // W1
    int e = (i4 - 1048576) * 4;
    float4 v = *(const float4*)(W1 + e);
    ushort4 o; o.x = f2bf(v.x); o.y = f2bf(v.y); o.z = f2bf(v.z); o.w = f2bf(v.w);
    *(ushort4*)(W1b + e) = o;
  } else if (i4 < 1179648) {                // W2
    int e = (i4 - 1114112) * 4;
    float4 v = *(const float4*)(W2 + e);
    ushort4 o; o.x = f2bf(v.x); o.y = f2bf(v.y); o.z = f2bf(v.z); o.w = f2bf(v.w);
    *(ushort4*)(W2b + e) = o;
  } else if (i4 < 1181184) {                // bias: 6144 elems
    int e = (i4 - 1179648) * 4;
    int l = e / 1536, n = e - l * 1536;
#pragma unroll
    for (int t = 0; t < 4; ++t) {
      int nn = n + t;
      bQKV[e + t] = (nn < 512) ? bq[l * 512 + nn] * QSCALE
                               : bkv[l * 1024 + (nn - 512)];
    }
  }
}

// ---------------------------------------------------------------------------
// bf16 MFMA GEMM for QKV: 128x128 tile, BK=64 (8 barrier-pairs instead of
// 16 — m233: the 2-phase critical path is stage+vmcnt+barrier), 4 waves,
// XCD-swizzled. LDS 32KB. Row stride is 128B so fragment reads would be a
// 16-way same-bank conflict; fixed by the round-8-verified slot-XOR
// (slot ^= row&7) applied on the GLOBAL source (gload_lds dest stays
// linear) and on the read offset (same involution, G21).
// M=10240, N=1536, K=512. xcd=bid&7 owns 10 row-stripes x 12 col-blocks.
// ---------------------------------------------------------------------------
#define GBK 32   // (oproj keeps BK=32)
#define QBK 64

__global__ __launch_bounds__(256)
void gemm_qkv(const u16* __restrict__ A, const u16* __restrict__ Bw,
              const float* __restrict__ bias, u16* __restrict__ Cout) {
  __shared__ __align__(16) u16 As[128 * QBK];   // 16KB
  __shared__ __align__(16) u16 Bs[128 * QBK];   // 16KB
  const int tid = threadIdx.x;
  const int wid = tid >> 6;
  const int lane = tid & 63;
  const int bid = blockIdx.x;
  const int xcd = bid & 7;
  const int t = bid >> 3;                 // 0..119
  const int cb = t % 12;
  const int rb = xcd * 10 + t / 12;
  const int bm = rb * 128;
  const int bn = cb * 128;
  const int wr = wid >> 1, wc = wid & 1;

  // staging: thread covers chunk c = r*256 + tid (r=0..3);
  // row = r*32 + (tid>>3), LDS slot = tid&7 (linear dest);
  // global slot pre-swizzled: (tid&7) ^ (row&7) so data lands bank-spread.
  const int srow = tid >> 3;                          // 0..31
  const int sko  = (((tid & 7) ^ (srow & 7)) << 3);   // element offset

  f32x4 acc[4][4] = {};

  const u16* AgS = A  + (size_t)(bm + srow) * D_ + sko;
  const u16* BgS = Bw + (size_t)(bn + srow) * D_ + sko;
  u16* AsS = &As[wid * 512];              // wave-uniform chunk base (64*8 u16)
  u16* BsS = &Bs[wid * 512];

  const int lrow = lane & 15;
  const int lg   = lane >> 4;             // k-group 0..3 within K=32

  for (int k0 = 0; k0 < D_; k0 += QBK) {
    __syncthreads();                      // prior tile fully consumed
#pragma unroll
    for (int r = 0; r < 4; ++r) {
      gload_lds16(AgS + (size_t)(r * 32) * D_ + k0, AsS + r * 2048);
      gload_lds16(BgS + (size_t)(r * 32) * D_ + k0, BsS + r * 2048);
    }
    __syncthreads();                      // drains vmcnt -> tile ready

#pragma unroll
    for (int kk = 0; kk < 2; ++kk) {
      const int sl = (((kk * 4) + lg) ^ (lrow & 7)) << 4;   // swizzled byte slot
      bf16x8 afrag[4], bfrag[4];
#pragma unroll
      for (int m = 0; m < 4; ++m) {
        int row = wr * 64 + m * 16 + lrow;
        afrag[m] = *(const bf16x8*)((const char*)As + row * 128 + sl);
      }
#pragma unroll
      for (int n = 0; n < 4; ++n) {
        int col = wc * 64 + n * 16 + lrow;
        bfrag[n] = *(const bf16x8*)((const char*)Bs + col * 128 + sl);
      }
#pragma unroll
      for (int m = 0; m < 4; ++m)
#pragma unroll
        for (int n = 0; n < 4; ++n)
          acc[m][n] = __builtin_amdgcn_mfma_f32_16x16x32_bf16(
              afrag[m], bfrag[n], acc[m][n], 0, 0, 0);
    }
  }

  const int lcol  = lane & 15;
  const int lrow4 = (lane >> 4) * 4;
#pragma unroll
  for (int m = 0; m < 4; ++m) {
    int rowbase = bm + wr * 64 + m * 16 + lrow4;
#pragma unroll
    for (int n = 0; n < 4; ++n) {
      int col = bn + wc * 64 + n * 16 + lcol;
      float bv = bias[col];
#pragma unroll
      for (int j = 0; j < 4; ++j) {
        int row = rowbase + j;
        Cout[(size_t)row * CH_ + col] = f2bf(acc[m][n][j] + bv);
      }
    }
  }
}

// ---------------------------------------------------------------------------
// O-proj: pure N-tiled GEMM + residual, fp32 out (in-place X).
// 128x128 tile, BK=32, 4 waves, grid 320 = 8 xcd x 4 cb x 10 rb. (unchanged)
// ---------------------------------------------------------------------------
__global__ __launch_bounds__(256)
void gemm_oproj(const u16* __restrict__ A, const u16* __restrict__ Bw,
                const float* __restrict__ bias, float* __restrict__ Xio) {
  __shared__ __align__(16) u16 As[128 * GBK];
  __shared__ __align__(16) u16 Bs[128 * GBK];
  const int tid = threadIdx.x;
  const int wid = tid >> 6;
  const int lane = tid & 63;
  const int bid = blockIdx.x;
  const int xcd = bid & 7;
  const int t = bid >> 3;                 // 0..39
  const int cb = t & 3;
  const int rb = xcd * 10 + (t >> 2);
  const int bm = rb * 128;
  const int bn = cb * 128;
  const int wr = wid >> 1, wc = wid & 1;

  const int srow = tid >> 2;
  const int skoff = (tid & 3) << 3;

  f32x4 acc[4][4] = {};

  const u16* Ag0 = A  + (size_t)(bm + srow)      * D_ + skoff;
  const u16* Ag1 = A  + (size_t)(bm + 64 + srow) * D_ + skoff;
  const u16* Bg0 = Bw + (size_t)(bn + srow)      * D_ + skoff;
  const u16* Bg1 = Bw + (size_t)(bn + 64 + srow) * D_ + skoff;
  u16* AsW0 = &As[(size_t)(wid * 16)      * GBK];
  u16* AsW1 = &As[(size_t)(64 + wid * 16) * GBK];
  u16* BsW0 = &Bs[(size_t)(wid * 16)      * GBK];
  u16* BsW1 = &Bs[(size_t)(64 + wid * 16) * GBK];

  const int lrow = lane & 15;
  const int lko  = (lane >> 4) * 16;

  for (int k0 = 0; k0 < D_; k0 += GBK) {
    __syncthreads();
    gload_lds16(Ag0 + k0, AsW0);
    gload_lds16(Ag1 + k0, AsW1);
    gload_lds16(Bg0 + k0, BsW0);
    gload_lds16(Bg1 + k0, BsW1);
    __syncthreads();

    bf16x8 afrag[4], bfrag[4];
#pragma unroll
    for (int m = 0; m < 4; ++m) {
      int row = wr * 64 + m * 16 + lrow;
      afrag[m] = *(const bf16x8*)((const char*)As + row * (GBK * 2) + lko);
    }
#pragma unroll
    for (int n = 0; n < 4; ++n) {
      int col = wc * 64 + n * 16 + lrow;
      bfrag[n] = *(const bf16x8*)((const char*)Bs + col * (GBK * 2) + lko);
    }
#pragma unroll
    for (int m = 0; m < 4; ++m)
#pragma unroll
      for (int n = 0; n < 4; ++n)
        acc[m][n] = __builtin_amdgcn_mfma_f32_16x16x32_bf16(
            afrag[m], bfrag[n], acc[m][n], 0, 0, 0);
  }

  const int lcol  = lane & 15;
  const int lrow4 = (lane >> 4) * 4;
#pragma unroll
  for (int m = 0; m < 4; ++m) {
    int rowbase = bm + wr * 64 + m * 16 + lrow4;
#pragma unroll
    for (int n = 0; n < 4; ++n) {
      int col = bn + wc * 64 + n * 16 + lcol;
      float bv = bias[col];
#pragma unroll
      for (int j = 0; j < 4; ++j) {
        size_t idx = (size_t)(rowbase + j) * D_ + col;
        Xio[idx] = acc[m][n][j] + bv + Xio[idx];
      }
    }
  }
}

// ---------------------------------------------------------------------------
// Fused FFN: LN_ff (register prologue) -> FFN1(relu, H in regs->LDS) ->
// FFN2 + residual + LN_out (+ LN_in next). 16-row tiles, grid 640.
// MODE 1 (l<3): LN1 -> Xout fp32; LN2 -> OutBf bf16.   MODE 2: LN1 only.
// ---------------------------------------------------------------------------
template <int MODE>
__global__ __launch_bounds__(256)
void ffn_fused(const float* __restrict__ X,
               const float* __restrict__ gff, const float* __restrict__ bff,
               const u16* __restrict__ W1, const float* __restrict__ b1,
               const u16* __restrict__ W2, const float* __restrict__ b2,
               const float* __restrict__ g1, const float* __restrict__ b1o,
               const float* __restrict__ g2, const float* __restrict__ b2i,
               float* __restrict__ Xout, u16* __restrict__ OutBf) {
  __shared__ __align__(16) u16 Bs[512 * 32];    // 32KB: W1 (first 8KB) / W2
  __shared__ __align__(16) u16 Aln[16 * 512];   // 16KB swizzled; Hs overlays
  __shared__ float wsum[4][16], wss[4][16], mu_s[16], rs_s[16];
  u16* Hs = Aln;                                // 4KB overlay (post phase A)
  const int tid = threadIdx.x;
  const int wid = tid >> 6, lane = tid & 63;
  const int bm = blockIdx.x * 16;
  const int r  = tid >> 4;            // 0..15 row in tile
  const int jj = tid & 15;            // 16 lanes per row

  // ---- LN_ff prologue (in registers) ----
  {
    const float* xr = X + (size_t)(bm + r) * D_ + jj * 32;
    float v[32];
    float s = 0.f, ss = 0.f;
#pragma unroll
    for (int i = 0; i < 8; ++i) {
      float4 q = *(const float4*)(xr + i * 4);
      v[i * 4 + 0] = q.x; v[i * 4 + 1] = q.y;
      v[i * 4 + 2] = q.z; v[i * 4 + 3] = q.w;
      s  += q.x + q.y + q.z + q.w;
      ss += q.x * q.x + q.y * q.y + q.z * q.z + q.w * q.w;
    }
#pragma unroll
    for (int off = 1; off < 16; off <<= 1) {
      s  += __shfl_xor(s, off);
      ss += __shfl_xor(ss, off);
    }
    float mu = s * (1.0f / D_);
    float var = ss * (1.0f / D_) - mu * mu;
    if (var < 0.f) var = 0.f;
    float rs = rsqrtf(var + 1e-5f);
    char* Ab = (char*)Aln;
#pragma unroll
    for (int i = 0; i < 8; ++i) {
      int c0 = jj * 32 + i * 4;
      float4 g4 = *(const float4*)(gff + c0);
      float4 b4 = *(const float4*)(bff + c0);
      ushort4 o;
      o.x = f2bf((v[i * 4 + 0] - mu) * rs * g4.x + b4.x);
      o.y = f2bf((v[i * 4 + 1] - mu) * rs * g4.y + b4.y);
      o.z = f2bf((v[i * 4 + 2] - mu) * rs * g4.z + b4.z);
      o.w = f2bf((v[i * 4 + 3] - mu) * rs * g4.w + b4.w);
      int byteoff = (r * 1024 + c0 * 2) ^ ((r & 7) << 4);
      *(ushort4*)(Ab + byteoff) = o;
    }
  }
  __syncthreads();

  // ---- phase A: H = relu(LN_ff @ W1^T + b1), H in registers ----
  const int lrow = lane & 15;
  const int lko  = (lane >> 4) << 4;   // bytes
  const int l4 = lane >> 2;
  const int k8 = (lane & 3) << 3;
  f32x4 accA[2] = {};

  for (int k0 = 0; k0 < D_; k0 += 32) {
    if (k0) __syncthreads();
#pragma unroll
    for (int p = 0; p < 2; ++p) {
      int rowb = wid * 32 + p * 16 + l4;
      gload_lds16(W1 + (size_t)rowb * D_ + k0 + k8,
                  (char*)Bs + (wid * 32 + p * 16) * 64);
    }
    __syncthreads();
    bf16x8 af = *(const bf16x8*)((const char*)Aln +
                  ((lrow * 1024 + k0 * 2 + lko) ^ ((lrow & 7) << 4)));
    bf16x8 bf[2];
#pragma unroll
    for (int n = 0; n < 2; ++n)
      bf[n] = *(const bf16x8*)((const char*)Bs + (wid * 32 + n * 16 + lrow) * 64 + lko);
#pragma unroll
    for (int n = 0; n < 2; ++n)
      accA[n] = __builtin_amdgcn_mfma_f32_16x16x32_bf16(af, bf[n], accA[n], 0, 0, 0);
  }

  const int lcol = lane & 15;
  const int lr4 = (lane >> 4) * 4;
  __syncthreads();                     // all Aln/Bs reads complete

  // ---- hand H to LDS (bias + relu, swizzled; overlays Aln) ----
#pragma unroll
  for (int n = 0; n < 2; ++n) {
    int col = wid * 32 + n * 16 + lcol;
    float bv = b1[col];
#pragma unroll
    for (int j = 0; j < 4; ++j) {
      int rr = lr4 + j;
      float hv = fmaxf(accA[n][j] + bv, 0.f);
      int byteoff = (rr * 256 + col * 2) ^ ((rr & 7) << 4);
      *(u16*)((char*)Hs + byteoff) = f2bf(hv);
    }
  }

  // ---- phase B: FFN2 + residual + LN_out (+ LN_in) ----
  f32x4 acc[8] = {};
  for (int k0 = 0; k0 < FFN_; k0 += 32) {
    __syncthreads();                   // k0=0: Hs visible; else: reads done
#pragma unroll
    for (int p = 0; p < 8; ++p) {
      int row = wid * 128 + p * 16 + l4;
      gload_lds16(W2 + (size_t)row * FFN_ + k0 + k8,
                  (char*)Bs + (wid * 128 + p * 16) * 64);
    }
    __syncthreads();

    bf16x8 af = *(const bf16x8*)((const char*)Hs +
                  ((lrow * 256 + k0 * 2 + lko) ^ ((lrow & 7) << 4)));
    bf16x8 bf[8];
#pragma unroll
    for (int n = 0; n < 8; ++n)
      bf[n] = *(const bf16x8*)((const char*)Bs + (wid * 128 + n * 16 + lrow) * 64 + lko);
#pragma unroll
    for (int n = 0; n < 8; ++n)
      acc[n] = __builtin_amdgcn_mfma_f32_16x16x32_bf16(af, bf[n], acc[n], 0, 0, 0);
  }

  // ---- bias + residual ----
#pragma unroll
  for (int n = 0; n < 8; ++n) {
    int col = wid * 128 + n * 16 + lcol;
    float bv = b2[col];
#pragma unroll
    for (int j = 0; j < 4; ++j) {
      int row = bm + lr4 + j;
      acc[n][j] = acc[n][j] + bv + X[(size_t)row * D_ + col];
    }
  }

  // ---- LN pass 1 (ln_out) ----
  {
    float s0[4] = {}, s1[4] = {};
#pragma unroll
    for (int n = 0; n < 8; ++n)
#pragma unroll
      for (int j = 0; j < 4; ++j) {
        float v = acc[n][j];
        s0[j] += v; s1[j] += v * v;
      }
#pragma unroll
    for (int off = 1; off < 16; off <<= 1)
#pragma unroll
      for (int j = 0; j < 4; ++j) {
        s0[j] += __shfl_xor(s0[j], off);
        s1[j] += __shfl_xor(s1[j], off);
      }
    if ((lane & 15) == 0) {
#pragma unroll
      for (int j = 0; j < 4; ++j) {
        wsum[wid][lr4 + j] = s0[j]; wss[wid][lr4 + j] = s1[j];
      }
    }
  }
  __syncthreads();
  if (tid < 16) {
    float S  = wsum[0][tid] + wsum[1][tid] + wsum[2][tid] + wsum[3][tid];
    float SS = wss[0][tid] + wss[1][tid] + wss[2][tid] + wss[3][tid];
    float mu = S * (1.0f / D_);
    float var = SS * (1.0f / D_) - mu * mu;
    if (var < 0.f) var = 0.f;
    mu_s[tid] = mu; rs_s[tid] = rsqrtf(var + 1e-5f);
  }
  __syncthreads();

  float gg[8], bv2[8];
#pragma unroll
  for (int n = 0; n < 8; ++n) {
    int col = wid * 128 + n * 16 + lcol;
    gg[n] = g1[col]; bv2[n] = b1o[col];
  }
#pragma unroll
  for (int n = 0; n < 8; ++n) {
    int col = wid * 128 + n * 16 + lcol;
#pragma unroll
    for (int j = 0; j < 4; ++j) {
      int rr = lr4 + j;
      int row = bm + rr;
      float ln = (acc[n][j] - mu_s[rr]) * rs_s[rr] * gg[n] + bv2[n];
      Xout[(size_t)row * D_ + col] = ln;
      acc[n][j] = ln;
    }
  }

  if (MODE == 1) {
    // ---- LN pass 2 (ln_in next layer) ----
    __syncthreads();
    {
      float s0[4] = {}, s1[4] = {};
#pragma unroll
      for (int n = 0; n < 8; ++n)
#pragma unroll
        for (int j = 0; j < 4; ++j) {
          float v = acc[n][j];
          s0[j] += v; s1[j] += v * v;
        }
#pragma unroll
      for (int off = 1; off < 16; off <<= 1)
#pragma unroll
        for (int j = 0; j < 4; ++j) {
          s0[j] += __shfl_xor(s0[j], off);
          s1[j] += __shfl_xor(s1[j], off);
        }
      if ((lane & 15) == 0) {
#pragma unroll
        for (int j = 0; j < 4; ++j) {
          wsum[wid][lr4 + j] = s0[j]; wss[wid][lr4 + j] = s1[j];
        }
      }
    }
    __syncthreads();
    if (tid < 16) {
      float S  = wsum[0][tid] + wsum[1][tid] + wsum[2][tid] + wsum[3][tid];
      float SS = wss[0][tid] + wss[1][tid] + wss[2][tid] + wss[3][tid];
      float mu = S * (1.0f / D_);
      float var = SS * (1.0f / D_) - mu * mu;
      if (var < 0.f) var = 0.f;
      mu_s[tid] = mu; rs_s[tid] = rsqrtf(var + 1e-5f);
    }
    __syncthreads();
#pragma unroll
    for (int n = 0; n < 8; ++n) {
      int col = wid * 128 + n * 16 + lcol;
      gg[n] = g2[col]; bv2[n] = b2i[col];
    }
#pragma unroll
    for (int n = 0; n < 8; ++n) {
      int col = wid * 128 + n * 16 + lcol;
#pragma unroll
      for (int j = 0; j < 4; ++j) {
        int rr = lr4 + j;
        int row = bm + rr;
        float ln = (acc[n][j] - mu_s[rr]) * rs_s[rr] * gg[n] + bv2[n];
        OutBf[(size_t)row * D_ + col] = f2bf(ln);
      }
    }
  }
}

// ---------------------------------------------------------------------------
// Block-diagonal attention reading fused QKV (stride 1536), f32 LDS,
// vectorized loads. Scale pre-folded into Wq/bq. One block per (b, seg);
// wave h = head h. Segment rows: {s, 256+4s..+3}.
// ---------------------------------------------------------------------------
#define QLD 516
__global__ __launch_bounds__(256)
void attn_k(const u16* __restrict__ QKV, u16* __restrict__ O) {
  int bs = blockIdx.x;
  int b = bs >> 8, s = bs & 255;
  __shared__ float Qs[5][QLD];
  __shared__ float Ks[5][QLD];
  __shared__ float Vs[5][QLD];
  __shared__ float P[H_][5][5];
  int tid = threadIdx.x;
  int rows[5];
  rows[0] = s;
#pragma unroll
  for (int i = 1; i < 5; ++i) rows[i] = R_ + 4 * s + (i - 1);
  // 960 chunks of 8 bf16: mtx (Q/K/V) x 5 rows x 64 chunks
  for (int idx = tid; idx < 960; idx += 256) {
    int mtx = idx / 320;
    int rem = idx - mtx * 320;
    int i = rem >> 6, c8 = rem & 63;
    size_t base = ((size_t)b * TOT_ + rows[i]) * CH_ + mtx * 512 + c8 * 8;
    bf16x8 v = *(const bf16x8*)(QKV + base);
    float* dst = (mtx == 0) ? &Qs[i][c8 * 8] : (mtx == 1 ? &Ks[i][c8 * 8] : &Vs[i][c8 * 8]);
#pragma unroll
    for (int t = 0; t < 8; ++t) dst[t] = bf2f((u16)v[t]);
  }
  __syncthreads();
  int h = tid >> 6, lane = tid & 63;
  if (lane < 25) {
    int i = lane / 5, j = lane % 5;
    float sum = 0.f;
    const float* qp = &Qs[i][h * DH_];
    const float* kp = &Ks[j][h * DH_];
#pragma unroll 8
    for (int d = 0; d < DH_; ++d) sum += qp[d] * kp[d];
    P[h][i][j] = sum;
  }
  __syncthreads();
  if (lane < 5) {
    int i = lane;
    float m = P[h][i][0];
#pragma unroll
    for (int j = 1; j < 5; ++j) m = fmaxf(m, P[h][i][j]);
    float e[5], ssum = 0.f;
#pragma unroll
    for (int j = 0; j < 5; ++j) { e[j] = __expf(P[h][i][j] - m); ssum += e[j]; }
    float inv = 1.0f / ssum;
#pragma unroll
    for (int j = 0; j < 5; ++j) P[h][i][j] = e[j] * inv;
  }
  __syncthreads();
  for (int idx = lane; idx < 5 * DH_; idx += 64) {
    int i = idx >> 7, d = idx & (DH_ - 1);
    float o = 0.f;
#pragma unroll
    for (int j = 0; j < 5; ++j) o += P[h][i][j] * Vs[j][h * DH_ + d];
    O[((size_t)b * TOT_ + rows[i]) * D_ + h * DH_ + d] = f2bf(o);
  }
}

// ---------------------------------------------------------------------------
// mean over the 1024 u rows -> (B, D), two stages (128 + 16 blocks).
// ---------------------------------------------------------------------------
__global__ __launch_bounds__(256)
void mean_part_k(const float* __restrict__ X, float* __restrict__ part) {
  int d = blockIdx.x * 256 + threadIdx.x;
  int jc = blockIdx.y;
  int b = blockIdx.z;
  float acc = 0.f;
  const float* base = X + ((size_t)b * TOT_ + R_ + jc * 128) * D_ + d;
  for (int j = 0; j < 128; ++j) acc += base[(size_t)j * D_];
  part[((size_t)b * 8 + jc) * D_ + d] = acc;
}

__global__ __launch_bounds__(256)
void mean_final_k(const float* __restrict__ part, float* __restrict__ out) {
  int i = blockIdx.x * 256 + threadIdx.x;
  int b = i >> 9, d = i & (D_ - 1);
  float acc = 0.f;
#pragma unroll
  for (int c = 0; c < 8; ++c) acc += part[((size_t)b * 8 + c) * D_ + d];
  out[i] = acc * (1.0f / U_);
}

// ---------------------------------------------------------------------------
// Launch. Workspace layout (byte offsets):
//   X      @ 0          fp32 20,971,520
//   LNbuf  @ 20971520   bf16 10,485,760
//   QKV    @ 31457280   bf16 31,457,280
//   ATT    @ 62914560   bf16 10,485,760
//   part   @ 86507520   fp32    131,072
//   WQKVb  @ 86638592   bf16  6,291,456
//   Wob    @ 92930048   bf16  2,097,152
//   W1b    @ 95027200   bf16    524,288
//   W2b    @ 95551488   bf16    524,288
//   bQKV   @ 96075776   fp32     24,576
// ---------------------------------------------------------------------------
extern "C" void kernel_launch(void* const* d_in, const int* in_sizes, int n_in,
                              void* d_out, int out_size, void* d_ws, size_t ws_size,
                              hipStream_t stream) {
  const float* x      = (const float*)d_in[0];
  const float* Wq     = (const float*)d_in[1];
  const float* bq     = (const float*)d_in[2];
  const float* Wkv    = (const float*)d_in[3];
  const float* bkv    = (const float*)d_in[4];
  const float* Wo     = (const float*)d_in[5];
  const float* bo     = (const float*)d_in[6];
  const float* W1     = (const float*)d_in[7];
  const float* b1     = (const float*)d_in[8];
  const float* W2     = (const float*)d_in[9];
  const float* b2     = (const float*)d_in[10];
  const float* ln_in_g  = (const float*)d_in[11];
  const float* ln_in_b  = (const float*)d_in[12];
  const float* ff_ln_g  = (const float*)d_in[13];
  const float* ff_ln_b  = (const float*)d_in[14];
  const float* ln_out_g = (const float*)d_in[15];
  const float* ln_out_b = (const float*)d_in[16];
  float* out = (float*)d_out;

  char* wsb = (char*)d_ws;
  float* X     = (float*)wsb;
  u16*   LNbuf = (u16*)(wsb + 20971520);
  u16*   QKV   = (u16*)(wsb + 31457280);
  u16*   ATT   = (u16*)(wsb + 62914560);
  float* part  = (float*)(wsb + 86507520);
  u16*   WQKVb = (u16*)(wsb + 86638592);
  u16*   Wob   = (u16*)(wsb + 92930048);
  u16*   W1b   = (u16*)(wsb + 95027200);
  u16*   W2b   = (u16*)(wsb + 95551488);
  float* bQKV  = (float*)(wsb + 96075776);

  // merged setup: weight cvt/pack + gather+LN-in(0)
  cvt_gather_k<<<SETUP_GRID, 256, 0, stream>>>(Wq, Wkv, Wo, W1, W2, bq, bkv,
                                               WQKVb, Wob, W1b, W2b, bQKV,
                                               x, ln_in_g, ln_in_b, X, LNbuf);

  for (int l = 0; l < L_; ++l) {
    const u16* WQKV_l = WQKVb + (size_t)l * CH_ * D_;
    const u16* Wo_l   = Wob   + (size_t)l * D_ * D_;
    const u16* W1_l   = W1b   + (size_t)l * FFN_ * D_;
    const u16* W2_l   = W2b   + (size_t)l * D_ * FFN_;
    const float* bQKV_l = bQKV + (size_t)l * CH_;
    const float* bo_l = bo + (size_t)l * D_;
    const float* b1_l = b1 + (size_t)l * FFN_;
    const float* b2_l = b2 + (size_t)l * D_;

    // QKV = LNbuf @ WQKV^T + bQKV  (BK=64, swizzled; Q pre-scaled)
    gemm_qkv<<<960, 256, 0, stream>>>(LNbuf, WQKV_l, bQKV_l, QKV);

    // attention -> ATT
    attn_k<<<B_ * NSEG_, 256, 0, stream>>>(QKV, ATT);

    // X += ATT @ Wo^T + bo
    gemm_oproj<<<320, 256, 0, stream>>>(ATT, Wo_l, bo_l, X);

    // fused FFN: LN_ff -> FFN1(relu) -> FFN2 + X + LN_out (+LN_in next)
    if (l < L_ - 1) {
      ffn_fused<1><<<M_ / 16, 256, 0, stream>>>(
          X, ff_ln_g + l * D_, ff_ln_b + l * D_,
          W1_l, b1_l, W2_l, b2_l,
          ln_out_g + l * D_, ln_out_b + l * D_,
          ln_in_g + (l + 1) * D_, ln_in_b + (l + 1) * D_,
          X, LNbuf);
    } else {
      ffn_fused<2><<<M_ / 16, 256, 0, stream>>>(
          X, ff_ln_g + l * D_, ff_ln_b + l * D_,
          W1_l, b1_l, W2_l, b2_l,
          ln_out_g + l * D_, ln_out_b + l * D_,
          nullptr, nullptr,
          X, nullptr);
    }
  }

  mean_part_k<<<dim3(2, 8, 8), 256, 0, stream>>>(X, part);
  mean_final_k<<<(B_ * D_) / 256, 256, 0, stream>>>(part, out);
}

// Round 16
// 356.359 us; speedup vs baseline: 1.1478x; 1.0195x over previous
//
#include <hip/hip_runtime.h>
#include <cstdint>
#include <cstddef>

// Problem constants
#define D_    512
#define H_    4
#define DH_   128
#define FFN_  128
#define L_    4
#define B_    8
#define T_    1025
#define U_    1024
#define NSEG_ 256
#define R_    256
#define TOT_  1280            // R + U
#define M_    (B_*TOT_)       // 10240 rows
#define CH_   1536            // QKV channels

typedef __attribute__((ext_vector_type(8))) short bf16x8;
typedef __attribute__((ext_vector_type(4))) float f32x4;
typedef unsigned short u16;

__device__ __forceinline__ u16 f2bf(float f) {
  unsigned u = __builtin_bit_cast(unsigned, f);
  u += 0x7fff + ((u >> 16) & 1);           // round-to-nearest-even
  return (u16)(u >> 16);
}
__device__ __forceinline__ float bf2f(u16 h) {
  unsigned u = ((unsigned)h) << 16;
  return __builtin_bit_cast(float, u);
}

__device__ __forceinline__ void gload_lds16(const void* g, void* l) {
  __builtin_amdgcn_global_load_lds(
      (const __attribute__((address_space(1))) unsigned*)g,
      (__attribute__((address_space(3))) unsigned*)l, 16, 0, 0);
}

#define QSCALE 0.08838834764831845f   // 128^-0.5, folded into Wq/bq

#define CVT_BLOCKS 4614
#define SETUP_GRID (CVT_BLOCKS + M_)   // 4614 cvt blocks + 10240 gather rows

// ---------------------------------------------------------------------------
// merged one-shot setup: weight cvt/pack (blocks 0..4613) + gather+LN-in(0)
// (blocks 4614..14853). Wq/bq are pre-scaled by QSCALE so attention skips it.
// ---------------------------------------------------------------------------
__global__ __launch_bounds__(256)
void cvt_gather_k(const float* __restrict__ Wq, const float* __restrict__ Wkv,
                  const float* __restrict__ Wo, const float* __restrict__ W1,
                  const float* __restrict__ W2, const float* __restrict__ bq,
                  const float* __restrict__ bkv,
                  u16* __restrict__ WQKVb, u16* __restrict__ Wob,
                  u16* __restrict__ W1b, u16* __restrict__ W2b,
                  float* __restrict__ bQKV,
                  const float* __restrict__ x, const float* __restrict__ g,
                  const float* __restrict__ bb, float* __restrict__ X,
                  u16* __restrict__ LNb) {
  __shared__ float red[10];
  const int bid = blockIdx.x;
  const int tid = threadIdx.x;

  if (bid >= CVT_BLOCKS) {
    // ---- gather + LN-in(layer 0) ----
    int row = bid - CVT_BLOCKS;
    int b = row / TOT_, p = row % TOT_;
    int t = (p < R_) ? ((p < R_ - 1) ? 4 * (p + 1) : (T_ - 1)) : (p - R_);
    const float* xr = x + ((size_t)b * T_ + t) * D_;
    float e0 = xr[tid], e1 = xr[tid + 256];
    X[(size_t)row * D_ + tid] = e0;
    X[(size_t)row * D_ + tid + 256] = e1;
    float s = e0 + e1, ss = e0 * e0 + e1 * e1;
#pragma unroll
    for (int off = 32; off > 0; off >>= 1) {
      s  += __shfl_down(s, off);
      ss += __shfl_down(ss, off);
    }
    int wid = tid >> 6, lane = tid & 63;
    if (lane == 0) { red[wid] = s; red[4 + wid] = ss; }
    __syncthreads();
    if (tid == 0) {
      float S = red[0] + red[1] + red[2] + red[3];
      float SS = red[4] + red[5] + red[6] + red[7];
      float mu = S * (1.0f / D_);
      float var = SS * (1.0f / D_) - mu * mu;
      if (var < 0.f) var = 0.f;
      red[8] = mu; red[9] = rsqrtf(var + 1e-5f);
    }
    __syncthreads();
    float mu = red[8], rs = red[9];
    u16* yr = LNb + (size_t)row * D_;
    yr[tid]       = f2bf((e0 - mu) * rs * g[tid]       + bb[tid]);
    yr[tid + 256] = f2bf((e1 - mu) * rs * g[tid + 256] + bb[tid + 256]);
    return;
  }

  // ---- weight conversion / packing ----
  int i4 = bid * 256 + tid;
  if (i4 < 786432) {                        // WQKV: 3,145,728 elems
    int e = i4 * 4;
    int l = e / 786432;
    int rem = e - l * 786432;
    int n = rem >> 9, k = rem & 511;
    const float* src = (n < 512) ? (Wq + (size_t)l * 262144 + n * 512 + k)
                                 : (Wkv + (size_t)l * 524288 + (n - 512) * 512 + k);
    float4 v = *(const float4*)src;
    if (n < 512) { v.x *= QSCALE; v.y *= QSCALE; v.z *= QSCALE; v.w *= QSCALE; }
    ushort4 o; o.x = f2bf(v.x); o.y = f2bf(v.y); o.z = f2bf(v.z); o.w = f2bf(v.w);
    *(ushort4*)(WQKVb + e) = o;
  } else if (i4 < 1048576) {                // Wo
    int e = (i4 - 786432) * 4;
    float4 v = *(const float4*)(Wo + e);
    ushort4 o; o.x = f2bf(v.x); o.y = f2bf(v.y); o.z = f2bf(v.z); o.w = f2bf(v.w);
    *(ushort4*)(Wob + e) = o;
  } else if (i4 < 1114112) {                // W1
    int e = (i4 - 1048576) * 4;
    float4 v = *(const float4*)(W1 + e);
    ushort4 o; o.x = f2bf(v.x); o.y = f2bf(v.y); o.z = f2bf(v.z); o.w = f2bf(v.w);
    *(ushort4*)(W1b + e) = o;
  } else if (i4 < 1179648) {                // W2
    int e = (i4 - 1114112) * 4;
    float4 v = *(const float4*)(W2 + e);
    ushort4 o; o.x = f2bf(v.x); o.y = f2bf(v.y); o.z = f2bf(v.z); o.w = f2bf(v.w);
    *(ushort4*)(W2b + e) = o;
  } else if (i4 < 1181184) {                // bias: 6144 elems
    int e = (i4 - 1179648) * 4;
    int l = e / 1536, n = e - l * 1536;
#pragma unroll
    for (int t = 0; t < 4; ++t) {
      int nn = n + t;
      bQKV[e + t] = (nn < 512) ? bq[l * 512 + nn] * QSCALE
                               : bkv[l * 1024 + (nn - 512)];
    }
  }
}

// ---------------------------------------------------------------------------
// bf16 MFMA GEMM for QKV: 128x128 tile, BK=64 (8 barrier-pairs), 4 waves,
// XCD-swizzled, slot-XOR LDS swizzle (both sides, G21). LDS 32KB.
// M=10240, N=1536, K=512. xcd=bid&7 owns 10 row-stripes x 12 col-blocks.
// ---------------------------------------------------------------------------
#define GBK 32
#define QBK 64

__global__ __launch_bounds__(256)
void gemm_qkv(const u16* __restrict__ A, const u16* __restrict__ Bw,
              const float* __restrict__ bias, u16* __restrict__ Cout) {
  __shared__ __align__(16) u16 As[128 * QBK];   // 16KB
  __shared__ __align__(16) u16 Bs[128 * QBK];   // 16KB
  const int tid = threadIdx.x;
  const int wid = tid >> 6;
  const int lane = tid & 63;
  const int bid = blockIdx.x;
  const int xcd = bid & 7;
  const int t = bid >> 3;                 // 0..119
  const int cb = t % 12;
  const int rb = xcd * 10 + t / 12;
  const int bm = rb * 128;
  const int bn = cb * 128;
  const int wr = wid >> 1, wc = wid & 1;

  const int srow = tid >> 3;                          // 0..31
  const int sko  = (((tid & 7) ^ (srow & 7)) << 3);   // element offset

  f32x4 acc[4][4] = {};

  const u16* AgS = A  + (size_t)(bm + srow) * D_ + sko;
  const u16* BgS = Bw + (size_t)(bn + srow) * D_ + sko;
  u16* AsS = &As[wid * 512];              // wave-uniform chunk base (64*8 u16)
  u16* BsS = &Bs[wid * 512];

  const int lrow = lane & 15;
  const int lg   = lane >> 4;             // k-group 0..3 within K=32

  for (int k0 = 0; k0 < D_; k0 += QBK) {
    __syncthreads();                      // prior tile fully consumed
#pragma unroll
    for (int r = 0; r < 4; ++r) {
      gload_lds16(AgS + (size_t)(r * 32) * D_ + k0, AsS + r * 2048);
      gload_lds16(BgS + (size_t)(r * 32) * D_ + k0, BsS + r * 2048);
    }
    __syncthreads();                      // drains vmcnt -> tile ready

#pragma unroll
    for (int kk = 0; kk < 2; ++kk) {
      const int sl = (((kk * 4) + lg) ^ (lrow & 7)) << 4;   // swizzled byte slot
      bf16x8 afrag[4], bfrag[4];
#pragma unroll
      for (int m = 0; m < 4; ++m) {
        int row = wr * 64 + m * 16 + lrow;
        afrag[m] = *(const bf16x8*)((const char*)As + row * 128 + sl);
      }
#pragma unroll
      for (int n = 0; n < 4; ++n) {
        int col = wc * 64 + n * 16 + lrow;
        bfrag[n] = *(const bf16x8*)((const char*)Bs + col * 128 + sl);
      }
#pragma unroll
      for (int m = 0; m < 4; ++m)
#pragma unroll
        for (int n = 0; n < 4; ++n)
          acc[m][n] = __builtin_amdgcn_mfma_f32_16x16x32_bf16(
              afrag[m], bfrag[n], acc[m][n], 0, 0, 0);
    }
  }

  const int lcol  = lane & 15;
  const int lrow4 = (lane >> 4) * 4;
#pragma unroll
  for (int m = 0; m < 4; ++m) {
    int rowbase = bm + wr * 64 + m * 16 + lrow4;
#pragma unroll
    for (int n = 0; n < 4; ++n) {
      int col = bn + wc * 64 + n * 16 + lcol;
      float bv = bias[col];
#pragma unroll
      for (int j = 0; j < 4; ++j) {
        int row = rowbase + j;
        Cout[(size_t)row * CH_ + col] = f2bf(acc[m][n][j] + bv);
      }
    }
  }
}

// ---------------------------------------------------------------------------
// O-proj: pure N-tiled GEMM + residual, fp32 out (in-place X).
// 128x128 tile, BK=64 (8 barrier-pairs, same transformation as gemm_qkv),
// slot-XOR swizzle both sides. Grid 320 = 8 xcd x 4 cb x 10 rb.
// ---------------------------------------------------------------------------
__global__ __launch_bounds__(256)
void gemm_oproj(const u16* __restrict__ A, const u16* __restrict__ Bw,
                const float* __restrict__ bias, float* __restrict__ Xio) {
  __shared__ __align__(16) u16 As[128 * QBK];   // 16KB
  __shared__ __align__(16) u16 Bs[128 * QBK];   // 16KB
  const int tid = threadIdx.x;
  const int wid = tid >> 6;
  const int lane = tid & 63;
  const int bid = blockIdx.x;
  const int xcd = bid & 7;
  const int t = bid >> 3;                 // 0..39
  const int cb = t & 3;
  const int rb = xcd * 10 + (t >> 2);
  const int bm = rb * 128;
  const int bn = cb * 128;
  const int wr = wid >> 1, wc = wid & 1;

  const int srow = tid >> 3;                          // 0..31
  const int sko  = (((tid & 7) ^ (srow & 7)) << 3);

  f32x4 acc[4][4] = {};

  const u16* AgS = A  + (size_t)(bm + srow) * D_ + sko;
  const u16* BgS = Bw + (size_t)(bn + srow) * D_ + sko;
  u16* AsS = &As[wid * 512];
  u16* BsS = &Bs[wid * 512];

  const int lrow = lane & 15;
  const int lg   = lane >> 4;

  for (int k0 = 0; k0 < D_; k0 += QBK) {
    __syncthreads();
#pragma unroll
    for (int r = 0; r < 4; ++r) {
      gload_lds16(AgS + (size_t)(r * 32) * D_ + k0, AsS + r * 2048);
      gload_lds16(BgS + (size_t)(r * 32) * D_ + k0, BsS + r * 2048);
    }
    __syncthreads();

#pragma unroll
    for (int kk = 0; kk < 2; ++kk) {
      const int sl = (((kk * 4) + lg) ^ (lrow & 7)) << 4;
      bf16x8 afrag[4], bfrag[4];
#pragma unroll
      for (int m = 0; m < 4; ++m) {
        int row = wr * 64 + m * 16 + lrow;
        afrag[m] = *(const bf16x8*)((const char*)As + row * 128 + sl);
      }
#pragma unroll
      for (int n = 0; n < 4; ++n) {
        int col = wc * 64 + n * 16 + lrow;
        bfrag[n] = *(const bf16x8*)((const char*)Bs + col * 128 + sl);
      }
#pragma unroll
      for (int m = 0; m < 4; ++m)
#pragma unroll
        for (int n = 0; n < 4; ++n)
          acc[m][n] = __builtin_amdgcn_mfma_f32_16x16x32_bf16(
              afrag[m], bfrag[n], acc[m][n], 0, 0, 0);
    }
  }

  const int lcol  = lane & 15;
  const int lrow4 = (lane >> 4) * 4;
#pragma unroll
  for (int m = 0; m < 4; ++m) {
    int rowbase = bm + wr * 64 + m * 16 + lrow4;
#pragma unroll
    for (int n = 0; n < 4; ++n) {
      int col = bn + wc * 64 + n * 16 + lcol;
      float bv = bias[col];
#pragma unroll
      for (int j = 0; j < 4; ++j) {
        size_t idx = (size_t)(rowbase + j) * D_ + col;
        Xio[idx] = acc[m][n][j] + bv + Xio[idx];
      }
    }
  }
}

// ---------------------------------------------------------------------------
// Fused FFN: LN_ff (register prologue) -> FFN1(relu, H in regs->LDS) ->
// FFN2 + residual + LN_out (+ LN_in next). 16-row tiles, grid 640.
// MODE 1 (l<3): LN1 -> Xout fp32; LN2 -> OutBf bf16.   MODE 2: LN1 only.
// ---------------------------------------------------------------------------
template <int MODE>
__global__ __launch_bounds__(256)
void ffn_fused(const float* __restrict__ X,
               const float* __restrict__ gff, const float* __restrict__ bff,
               const u16* __restrict__ W1, const float* __restrict__ b1,
               const u16* __restrict__ W2, const float* __restrict__ b2,
               const float* __restrict__ g1, const float* __restrict__ b1o,
               const float* __restrict__ g2, const float* __restrict__ b2i,
               float* __restrict__ Xout, u16* __restrict__ OutBf) {
  __shared__ __align__(16) u16 Bs[512 * 32];    // 32KB: W1 (first 8KB) / W2
  __shared__ __align__(16) u16 Aln[16 * 512];   // 16KB swizzled; Hs overlays
  __shared__ float wsum[4][16], wss[4][16], mu_s[16], rs_s[16];
  u16* Hs = Aln;                                // 4KB overlay (post phase A)
  const int tid = threadIdx.x;
  const int wid = tid >> 6, lane = tid & 63;
  const int bm = blockIdx.x * 16;
  const int r  = tid >> 4;            // 0..15 row in tile
  const int jj = tid & 15;            // 16 lanes per row

  // ---- LN_ff prologue (in registers) ----
  {
    const float* xr = X + (size_t)(bm + r) * D_ + jj * 32;
    float v[32];
    float s = 0.f, ss = 0.f;
#pragma unroll
    for (int i = 0; i < 8; ++i) {
      float4 q = *(const float4*)(xr + i * 4);
      v[i * 4 + 0] = q.x; v[i * 4 + 1] = q.y;
      v[i * 4 + 2] = q.z; v[i * 4 + 3] = q.w;
      s  += q.x + q.y + q.z + q.w;
      ss += q.x * q.x + q.y * q.y + q.z * q.z + q.w * q.w;
    }
#pragma unroll
    for (int off = 1; off < 16; off <<= 1) {
      s  += __shfl_xor(s, off);
      ss += __shfl_xor(ss, off);
    }
    float mu = s * (1.0f / D_);
    float var = ss * (1.0f / D_) - mu * mu;
    if (var < 0.f) var = 0.f;
    float rs = rsqrtf(var + 1e-5f);
    char* Ab = (char*)Aln;
#pragma unroll
    for (int i = 0; i < 8; ++i) {
      int c0 = jj * 32 + i * 4;
      float4 g4 = *(const float4*)(gff + c0);
      float4 b4 = *(const float4*)(bff + c0);
      ushort4 o;
      o.x = f2bf((v[i * 4 + 0] - mu) * rs * g4.x + b4.x);
      o.y = f2bf((v[i * 4 + 1] - mu) * rs * g4.y + b4.y);
      o.z = f2bf((v[i * 4 + 2] - mu) * rs * g4.z + b4.z);
      o.w = f2bf((v[i * 4 + 3] - mu) * rs * g4.w + b4.w);
      int byteoff = (r * 1024 + c0 * 2) ^ ((r & 7) << 4);
      *(ushort4*)(Ab + byteoff) = o;
    }
  }
  __syncthreads();

  // ---- phase A: H = relu(LN_ff @ W1^T + b1), H in registers ----
  const int lrow = lane & 15;
  const int lko  = (lane >> 4) << 4;   // bytes
  const int l4 = lane >> 2;
  const int k8 = (lane & 3) << 3;
  f32x4 accA[2] = {};

  for (int k0 = 0; k0 < D_; k0 += 32) {
    if (k0) __syncthreads();
#pragma unroll
    for (int p = 0; p < 2; ++p) {
      int rowb = wid * 32 + p * 16 + l4;
      gload_lds16(W1 + (size_t)rowb * D_ + k0 + k8,
                  (char*)Bs + (wid * 32 + p * 16) * 64);
    }
    __syncthreads();
    bf16x8 af = *(const bf16x8*)((const char*)Aln +
                  ((lrow * 1024 + k0 * 2 + lko) ^ ((lrow & 7) << 4)));
    bf16x8 bf[2];
#pragma unroll
    for (int n = 0; n < 2; ++n)
      bf[n] = *(const bf16x8*)((const char*)Bs + (wid * 32 + n * 16 + lrow) * 64 + lko);
#pragma unroll
    for (int n = 0; n < 2; ++n)
      accA[n] = __builtin_amdgcn_mfma_f32_16x16x32_bf16(af, bf[n], accA[n], 0, 0, 0);
  }

  const int lcol = lane & 15;
  const int lr4 = (lane >> 4) * 4;
  __syncthreads();                     // all Aln/Bs reads complete

  // ---- hand H to LDS (bias + relu, swizzled; overlays Aln) ----
#pragma unroll
  for (int n = 0; n < 2; ++n) {
    int col = wid * 32 + n * 16 + lcol;
    float bv = b1[col];
#pragma unroll
    for (int j = 0; j < 4; ++j) {
      int rr = lr4 + j;
      float hv = fmaxf(accA[n][j] + bv, 0.f);
      int byteoff = (rr * 256 + col * 2) ^ ((rr & 7) << 4);
      *(u16*)((char*)Hs + byteoff) = f2bf(hv);
    }
  }

  // ---- phase B: FFN2 + residual + LN_out (+ LN_in) ----
  f32x4 acc[8] = {};
  for (int k0 = 0; k0 < FFN_; k0 += 32) {
    __syncthreads();                   // k0=0: Hs visible; else: reads done
#pragma unroll
    for (int p = 0; p < 8; ++p) {
      int row = wid * 128 + p * 16 + l4;
      gload_lds16(W2 + (size_t)row * FFN_ + k0 + k8,
                  (char*)Bs + (wid * 128 + p * 16) * 64);
    }
    __syncthreads();

    bf16x8 af = *(const bf16x8*)((const char*)Hs +
                  ((lrow * 256 + k0 * 2 + lko) ^ ((lrow & 7) << 4)));
    bf16x8 bf[8];
#pragma unroll
    for (int n = 0; n < 8; ++n)
      bf[n] = *(const bf16x8*)((const char*)Bs + (wid * 128 + n * 16 + lrow) * 64 + lko);
#pragma unroll
    for (int n = 0; n < 8; ++n)
      acc[n] = __builtin_amdgcn_mfma_f32_16x16x32_bf16(af, bf[n], acc[n], 0, 0, 0);
  }

  // ---- bias + residual ----
#pragma unroll
  for (int n = 0; n < 8; ++n) {
    int col = wid * 128 + n * 16 + lcol;
    float bv = b2[col];
#pragma unroll
    for (int j = 0; j < 4; ++j) {
      int row = bm + lr4 + j;
      acc[n][j] = acc[n][j] + bv + X[(size_t)row * D_ + col];
    }
  }

  // ---- LN pass 1 (ln_out) ----
  {
    float s0[4] = {}, s1[4] = {};
#pragma unroll
    for (int n = 0; n < 8; ++n)
#pragma unroll
      for (int j = 0; j < 4; ++j) {
        float v = acc[n][j];
        s0[j] += v; s1[j] += v * v;
      }
#pragma unroll
    for (int off = 1; off < 16; off <<= 1)
#pragma unroll
      for (int j = 0; j < 4; ++j) {
        s0[j] += __shfl_xor(s0[j], off);
        s1[j] += __shfl_xor(s1[j], off);
      }
    if ((lane & 15) == 0) {
#pragma unroll
      for (int j = 0; j < 4; ++j) {
        wsum[wid][lr4 + j] = s0[j]; wss[wid][lr4 + j] = s1[j];
      }
    }
  }
  __syncthreads();
  if (tid < 16) {
    float S  = wsum[0][tid] + wsum[1][tid] + wsum[2][tid] + wsum[3][tid];
    float SS = wss[0][tid] + wss[1][tid] + wss[2][tid] + wss[3][tid];
    float mu = S * (1.0f / D_);
    float var = SS * (1.0f / D_) - mu * mu;
    if (var < 0.f) var = 0.f;
    mu_s[tid] = mu; rs_s[tid] = rsqrtf(var + 1e-5f);
  }
  __syncthreads();

  float gg[8], bv2[8];
#pragma unroll
  for (int n = 0; n < 8; ++n) {
    int col = wid * 128 + n * 16 + lcol;
    gg[n] = g1[col]; bv2[n] = b1o[col];
  }
#pragma unroll
  for (int n = 0; n < 8; ++n) {
    int col = wid * 128 + n * 16 + lcol;
#pragma unroll
    for (int j = 0; j < 4; ++j) {
      int rr = lr4 + j;
      int row = bm + rr;
      float ln = (acc[n][j] - mu_s[rr]) * rs_s[rr] * gg[n] + bv2[n];
      Xout[(size_t)row * D_ + col] = ln;
      acc[n][j] = ln;
    }
  }

  if (MODE == 1) {
    // ---- LN pass 2 (ln_in next layer) ----
    __syncthreads();
    {
      float s0[4] = {}, s1[4] = {};
#pragma unroll
      for (int n = 0; n < 8; ++n)
#pragma unroll
        for (int j = 0; j < 4; ++j) {
          float v = acc[n][j];
          s0[j] += v; s1[j] += v * v;
        }
#pragma unroll
      for (int off = 1; off < 16; off <<= 1)
#pragma unroll
        for (int j = 0; j < 4; ++j) {
          s0[j] += __shfl_xor(s0[j], off);
          s1[j] += __shfl_xor(s1[j], off);
        }
      if ((lane & 15) == 0) {
#pragma unroll
        for (int j = 0; j < 4; ++j) {
          wsum[wid][lr4 + j] = s0[j]; wss[wid][lr4 + j] = s1[j];
        }
      }
    }
    __syncthreads();
    if (tid < 16) {
      float S  = wsum[0][tid] + wsum[1][tid] + wsum[2][tid] + wsum[3][tid];
      float SS = wss[0][tid] + wss[1][tid] + wss[2][tid] + wss[3][tid];
      float mu = S * (1.0f / D_);
      float var = SS * (1.0f / D_) - mu * mu;
      if (var < 0.f) var = 0.f;
      mu_s[tid] = mu; rs_s[tid] = rsqrtf(var + 1e-5f);
    }
    __syncthreads();
#pragma unroll
    for (int n = 0; n < 8; ++n) {
      int col = wid * 128 + n * 16 + lcol;
      gg[n] = g2[col]; bv2[n] = b2i[col];
    }
#pragma unroll
    for (int n = 0; n < 8; ++n) {
      int col = wid * 128 + n * 16 + lcol;
#pragma unroll
      for (int j = 0; j < 4; ++j) {
        int rr = lr4 + j;
        int row = bm + rr;
        float ln = (acc[n][j] - mu_s[rr]) * rs_s[rr] * gg[n] + bv2[n];
        OutBf[(size_t)row * D_ + col] = f2bf(ln);
      }
    }
  }
}

// ---------------------------------------------------------------------------
// Block-diagonal attention reading fused QKV (stride 1536), f32 LDS,
// vectorized loads. Scale pre-folded into Wq/bq. One block per (b, seg);
// wave h = head h. Segment rows: {s, 256+4s..+3}.
// ---------------------------------------------------------------------------
#define QLD 516
__global__ __launch_bounds__(256)
void attn_k(const u16* __restrict__ QKV, u16* __restrict__ O) {
  int bs = blockIdx.x;
  int b = bs >> 8, s = bs & 255;
  __shared__ float Qs[5][QLD];
  __shared__ float Ks[5][QLD];
  __shared__ float Vs[5][QLD];
  __shared__ float P[H_][5][5];
  int tid = threadIdx.x;
  int rows[5];
  rows[0] = s;
#pragma unroll
  for (int i = 1; i < 5; ++i) rows[i] = R_ + 4 * s + (i - 1);
  // 960 chunks of 8 bf16: mtx (Q/K/V) x 5 rows x 64 chunks
  for (int idx = tid; idx < 960; idx += 256) {
    int mtx = idx / 320;
    int rem = idx - mtx * 320;
    int i = rem >> 6, c8 = rem & 63;
    size_t base = ((size_t)b * TOT_ + rows[i]) * CH_ + mtx * 512 + c8 * 8;
    bf16x8 v = *(const bf16x8*)(QKV + base);
    float* dst = (mtx == 0) ? &Qs[i][c8 * 8] : (mtx == 1 ? &Ks[i][c8 * 8] : &Vs[i][c8 * 8]);
#pragma unroll
    for (int t = 0; t < 8; ++t) dst[t] = bf2f((u16)v[t]);
  }
  __syncthreads();
  int h = tid >> 6, lane = tid & 63;
  if (lane < 25) {
    int i = lane / 5, j = lane % 5;
    float sum = 0.f;
    const float* qp = &Qs[i][h * DH_];
    const float* kp = &Ks[j][h * DH_];
#pragma unroll 8
    for (int d = 0; d < DH_; ++d) sum += qp[d] * kp[d];
    P[h][i][j] = sum;
  }
  __syncthreads();
  if (lane < 5) {
    int i = lane;
    float m = P[h][i][0];
#pragma unroll
    for (int j = 1; j < 5; ++j) m = fmaxf(m, P[h][i][j]);
    float e[5], ssum = 0.f;
#pragma unroll
    for (int j = 0; j < 5; ++j) { e[j] = __expf(P[h][i][j] - m); ssum += e[j]; }
    float inv = 1.0f / ssum;
#pragma unroll
    for (int j = 0; j < 5; ++j) P[h][i][j] = e[j] * inv;
  }
  __syncthreads();
  for (int idx = lane; idx < 5 * DH_; idx += 64) {
    int i = idx >> 7, d = idx & (DH_ - 1);
    float o = 0.f;
#pragma unroll
    for (int j = 0; j < 5; ++j) o += P[h][i][j] * Vs[j][h * DH_ + d];
    O[((size_t)b * TOT_ + rows[i]) * D_ + h * DH_ + d] = f2bf(o);
  }
}

// ---------------------------------------------------------------------------
// mean over the 1024 u rows -> (B, D), two stages (128 + 16 blocks).
// ---------------------------------------------------------------------------
__global__ __launch_bounds__(256)
void mean_part_k(const float* __restrict__ X, float* __restrict__ part) {
  int d = blockIdx.x * 256 + threadIdx.x;
  int jc = blockIdx.y;
  int b = blockIdx.z;
  float acc = 0.f;
  const float* base = X + ((size_t)b * TOT_ + R_ + jc * 128) * D_ + d;
  for (int j = 0; j < 128; ++j) acc += base[(size_t)j * D_];
  part[((size_t)b * 8 + jc) * D_ + d] = acc;
}

__global__ __launch_bounds__(256)
void mean_final_k(const float* __restrict__ part, float* __restrict__ out) {
  int i = blockIdx.x * 256 + threadIdx.x;
  int b = i >> 9, d = i & (D_ - 1);
  float acc = 0.f;
#pragma unroll
  for (int c = 0; c < 8; ++c) acc += part[((size_t)b * 8 + c) * D_ + d];
  out[i] = acc * (1.0f / U_);
}

// ---------------------------------------------------------------------------
// Launch. Workspace layout (byte offsets):
//   X      @ 0          fp32 20,971,520
//   LNbuf  @ 20971520   bf16 10,485,760
//   QKV    @ 31457280   bf16 31,457,280
//   ATT    @ 62914560   bf16 10,485,760
//   part   @ 86507520   fp32    131,072
//   WQKVb  @ 86638592   bf16  6,291,456
//   Wob    @ 92930048   bf16  2,097,152
//   W1b    @ 95027200   bf16    524,288
//   W2b    @ 95551488   bf16    524,288
//   bQKV   @ 96075776   fp32     24,576
// ---------------------------------------------------------------------------
extern "C" void kernel_launch(void* const* d_in, const int* in_sizes, int n_in,
                              void* d_out, int out_size, void* d_ws, size_t ws_size,
                              hipStream_t stream) {
  const float* x      = (const float*)d_in[0];
  const float* Wq     = (const float*)d_in[1];
  const float* bq     = (const float*)d_in[2];
  const float* Wkv    = (const float*)d_in[3];
  const float* bkv    = (const float*)d_in[4];
  const float* Wo     = (const float*)d_in[5];
  const float* bo     = (const float*)d_in[6];
  const float* W1     = (const float*)d_in[7];
  const float* b1     = (const float*)d_in[8];
  const float* W2     = (const float*)d_in[9];
  const float* b2     = (const float*)d_in[10];
  const float* ln_in_g  = (const float*)d_in[11];
  const float* ln_in_b  = (const float*)d_in[12];
  const float* ff_ln_g  = (const float*)d_in[13];
  const float* ff_ln_b  = (const float*)d_in[14];
  const float* ln_out_g = (const float*)d_in[15];
  const float* ln_out_b = (const float*)d_in[16];
  float* out = (float*)d_out;

  char* wsb = (char*)d_ws;
  float* X     = (float*)wsb;
  u16*   LNbuf = (u16*)(wsb + 20971520);
  u16*   QKV   = (u16*)(wsb + 31457280);
  u16*   ATT   = (u16*)(wsb + 62914560);
  float* part  = (float*)(wsb + 86507520);
  u16*   WQKVb = (u16*)(wsb + 86638592);
  u16*   Wob   = (u16*)(wsb + 92930048);
  u16*   W1b   = (u16*)(wsb + 95027200);
  u16*   W2b   = (u16*)(wsb + 95551488);
  float* bQKV  = (float*)(wsb + 96075776);

  // merged setup: weight cvt/pack + gather+LN-in(0)
  cvt_gather_k<<<SETUP_GRID, 256, 0, stream>>>(Wq, Wkv, Wo, W1, W2, bq, bkv,
                                               WQKVb, Wob, W1b, W2b, bQKV,
                                               x, ln_in_g, ln_in_b, X, LNbuf);

  for (int l = 0; l < L_; ++l) {
    const u16* WQKV_l = WQKVb + (size_t)l * CH_ * D_;
    const u16* Wo_l   = Wob   + (size_t)l * D_ * D_;
    const u16* W1_l   = W1b   + (size_t)l * FFN_ * D_;
    const u16* W2_l   = W2b   + (size_t)l * D_ * FFN_;
    const float* bQKV_l = bQKV + (size_t)l * CH_;
    const float* bo_l = bo + (size_t)l * D_;
    const float* b1_l = b1 + (size_t)l * FFN_;
    const float* b2_l = b2 + (size_t)l * D_;

    // QKV = LNbuf @ WQKV^T + bQKV  (BK=64, swizzled; Q pre-scaled)
    gemm_qkv<<<960, 256, 0, stream>>>(LNbuf, WQKV_l, bQKV_l, QKV);

    // attention -> ATT
    attn_k<<<B_ * NSEG_, 256, 0, stream>>>(QKV, ATT);

    // X += ATT @ Wo^T + bo  (BK=64, swizzled)
    gemm_oproj<<<320, 256, 0, stream>>>(ATT, Wo_l, bo_l, X);

    // fused FFN: LN_ff -> FFN1(relu) -> FFN2 + X + LN_out (+LN_in next)
    if (l < L_ - 1) {
      ffn_fused<1><<<M_ / 16, 256, 0, stream>>>(
          X, ff_ln_g + l * D_, ff_ln_b + l * D_,
          W1_l, b1_l, W2_l, b2_l,
          ln_out_g + l * D_, ln_out_b + l * D_,
          ln_in_g + (l + 1) * D_, ln_in_b + (l + 1) * D_,
          X, LNbuf);
    } else {
      ffn_fused<2><<<M_ / 16, 256, 0, stream>>>(
          X, ff_ln_g + l * D_, ff_ln_b + l * D_,
          W1_l, b1_l, W2_l, b2_l,
          ln_out_g + l * D_, ln_out_b + l * D_,
          nullptr, nullptr,
          X, nullptr);
    }
  }

  mean_part_k<<<dim3(2, 8, 8), 256, 0, stream>>>(X, part);
  mean_final_k<<<(B_ * D_) / 256, 256, 0, stream>>>(part, out);
}

// Round 17
// 354.979 us; speedup vs baseline: 1.1523x; 1.0039x over previous
//
#include <hip/hip_runtime.h>
#include <cstdint>
#include <cstddef>

// Problem constants
#define D_    512
#define H_    4
#define DH_   128
#define FFN_  128
#define L_    4
#define B_    8
#define T_    1025
#define U_    1024
#define NSEG_ 256
#define R_    256
#define TOT_  1280            // R + U
#define M_    (B_*TOT_)       // 10240 rows
#define CH_   1536            // QKV channels

typedef __attribute__((ext_vector_type(8))) short bf16x8;
typedef __attribute__((ext_vector_type(4))) float f32x4;
typedef unsigned short u16;

__device__ __forceinline__ u16 f2bf(float f) {
  unsigned u = __builtin_bit_cast(unsigned, f);
  u += 0x7fff + ((u >> 16) & 1);           // round-to-nearest-even
  return (u16)(u >> 16);
}
__device__ __forceinline__ float bf2f(u16 h) {
  unsigned u = ((unsigned)h) << 16;
  return __builtin_bit_cast(float, u);
}

__device__ __forceinline__ void gload_lds16(const void* g, void* l) {
  __builtin_amdgcn_global_load_lds(
      (const __attribute__((address_space(1))) unsigned*)g,
      (__attribute__((address_space(3))) unsigned*)l, 16, 0, 0);
}

#define QSCALE 0.08838834764831845f   // 128^-0.5, folded into Wq/bq

#define CVT_BLOCKS 4614
#define SETUP_GRID (CVT_BLOCKS + M_)   // 4614 cvt blocks + 10240 gather rows

// ---------------------------------------------------------------------------
// merged one-shot setup: weight cvt/pack (blocks 0..4613) + gather+LN-in(0)
// (blocks 4614..14853). Wq/bq are pre-scaled by QSCALE so attention skips it.
// ---------------------------------------------------------------------------
__global__ __launch_bounds__(256)
void cvt_gather_k(const float* __restrict__ Wq, const float* __restrict__ Wkv,
                  const float* __restrict__ Wo, const float* __restrict__ W1,
                  const float* __restrict__ W2, const float* __restrict__ bq,
                  const float* __restrict__ bkv,
                  u16* __restrict__ WQKVb, u16* __restrict__ Wob,
                  u16* __restrict__ W1b, u16* __restrict__ W2b,
                  float* __restrict__ bQKV,
                  const float* __restrict__ x, const float* __restrict__ g,
                  const float* __restrict__ bb, float* __restrict__ X,
                  u16* __restrict__ LNb) {
  __shared__ float red[10];
  const int bid = blockIdx.x;
  const int tid = threadIdx.x;

  if (bid >= CVT_BLOCKS) {
    // ---- gather + LN-in(layer 0) ----
    int row = bid - CVT_BLOCKS;
    int b = row / TOT_, p = row % TOT_;
    int t = (p < R_) ? ((p < R_ - 1) ? 4 * (p + 1) : (T_ - 1)) : (p - R_);
    const float* xr = x + ((size_t)b * T_ + t) * D_;
    float e0 = xr[tid], e1 = xr[tid + 256];
    X[(size_t)row * D_ + tid] = e0;
    X[(size_t)row * D_ + tid + 256] = e1;
    float s = e0 + e1, ss = e0 * e0 + e1 * e1;
#pragma unroll
    for (int off = 32; off > 0; off >>= 1) {
      s  += __shfl_down(s, off);
      ss += __shfl_down(ss, off);
    }
    int wid = tid >> 6, lane = tid & 63;
    if (lane == 0) { red[wid] = s; red[4 + wid] = ss; }
    __syncthreads();
    if (tid == 0) {
      float S = red[0] + red[1] + red[2] + red[3];
      float SS = red[4] + red[5] + red[6] + red[7];
      float mu = S * (1.0f / D_);
      float var = SS * (1.0f / D_) - mu * mu;
      if (var < 0.f) var = 0.f;
      red[8] = mu; red[9] = rsqrtf(var + 1e-5f);
    }
    __syncthreads();
    float mu = red[8], rs = red[9];
    u16* yr = LNb + (size_t)row * D_;
    yr[tid]       = f2bf((e0 - mu) * rs * g[tid]       + bb[tid]);
    yr[tid + 256] = f2bf((e1 - mu) * rs * g[tid + 256] + bb[tid + 256]);
    return;
  }

  // ---- weight conversion / packing ----
  int i4 = bid * 256 + tid;
  if (i4 < 786432) {                        // WQKV: 3,145,728 elems
    int e = i4 * 4;
    int l = e / 786432;
    int rem = e - l * 786432;
    int n = rem >> 9, k = rem & 511;
    const float* src = (n < 512) ? (Wq + (size_t)l * 262144 + n * 512 + k)
                                 : (Wkv + (size_t)l * 524288 + (n - 512) * 512 + k);
    float4 v = *(const float4*)src;
    if (n < 512) { v.x *= QSCALE; v.y *= QSCALE; v.z *= QSCALE; v.w *= QSCALE; }
    ushort4 o; o.x = f2bf(v.x); o.y = f2bf(v.y); o.z = f2bf(v.z); o.w = f2bf(v.w);
    *(ushort4*)(WQKVb + e) = o;
  } else if (i4 < 1048576) {                // Wo
    int e = (i4 - 786432) * 4;
    float4 v = *(const float4*)(Wo + e);
    ushort4 o; o.x = f2bf(v.x); o.y = f2bf(v.y); o.z = f2bf(v.z); o.w = f2bf(v.w);
    *(ushort4*)(Wob + e) = o;
  } else if (i4 < 1114112) {                // W1
    int e = (i4 - 1048576) * 4;
    float4 v = *(const float4*)(W1 + e);
    ushort4 o; o.x = f2bf(v.x); o.y = f2bf(v.y); o.z = f2bf(v.z); o.w = f2bf(v.w);
    *(ushort4*)(W1b + e) = o;
  } else if (i4 < 1179648) {                // W2
    int e = (i4 - 1114112) * 4;
    float4 v = *(const float4*)(W2 + e);
    ushort4 o; o.x = f2bf(v.x); o.y = f2bf(v.y); o.z = f2bf(v.z); o.w = f2bf(v.w);
    *(ushort4*)(W2b + e) = o;
  } else if (i4 < 1181184) {                // bias: 6144 elems
    int e = (i4 - 1179648) * 4;
    int l = e / 1536, n = e - l * 1536;
#pragma unroll
    for (int t = 0; t < 4; ++t) {
      int nn = n + t;
      bQKV[e + t] = (nn < 512) ? bq[l * 512 + nn] * QSCALE
                               : bkv[l * 1024 + (nn - 512)];
    }
  }
}

// ---------------------------------------------------------------------------
// bf16 MFMA GEMM for QKV: 128x128 tile, BK=64 (8 barrier-pairs), 4 waves,
// XCD-swizzled, slot-XOR LDS swizzle (both sides, G21). LDS 32KB.
// M=10240, N=1536, K=512. xcd=bid&7 owns 10 row-stripes x 12 col-blocks.
// ---------------------------------------------------------------------------
#define GBK 32
#define QBK 64

__global__ __launch_bounds__(256)
void gemm_qkv(const u16* __restrict__ A, const u16* __restrict__ Bw,
              const float* __restrict__ bias, u16* __restrict__ Cout) {
  __shared__ __align__(16) u16 As[128 * QBK];   // 16KB
  __shared__ __align__(16) u16 Bs[128 * QBK];   // 16KB
  const int tid = threadIdx.x;
  const int wid = tid >> 6;
  const int lane = tid & 63;
  const int bid = blockIdx.x;
  const int xcd = bid & 7;
  const int t = bid >> 3;                 // 0..119
  const int cb = t % 12;
  const int rb = xcd * 10 + t / 12;
  const int bm = rb * 128;
  const int bn = cb * 128;
  const int wr = wid >> 1, wc = wid & 1;

  const int srow = tid >> 3;                          // 0..31
  const int sko  = (((tid & 7) ^ (srow & 7)) << 3);   // element offset

  f32x4 acc[4][4] = {};

  const u16* AgS = A  + (size_t)(bm + srow) * D_ + sko;
  const u16* BgS = Bw + (size_t)(bn + srow) * D_ + sko;
  u16* AsS = &As[wid * 512];              // wave-uniform chunk base (64*8 u16)
  u16* BsS = &Bs[wid * 512];

  const int lrow = lane & 15;
  const int lg   = lane >> 4;             // k-group 0..3 within K=32

  for (int k0 = 0; k0 < D_; k0 += QBK) {
    __syncthreads();                      // prior tile fully consumed
#pragma unroll
    for (int r = 0; r < 4; ++r) {
      gload_lds16(AgS + (size_t)(r * 32) * D_ + k0, AsS + r * 2048);
      gload_lds16(BgS + (size_t)(r * 32) * D_ + k0, BsS + r * 2048);
    }
    __syncthreads();                      // drains vmcnt -> tile ready

#pragma unroll
    for (int kk = 0; kk < 2; ++kk) {
      const int sl = (((kk * 4) + lg) ^ (lrow & 7)) << 4;   // swizzled byte slot
      bf16x8 afrag[4], bfrag[4];
#pragma unroll
      for (int m = 0; m < 4; ++m) {
        int row = wr * 64 + m * 16 + lrow;
        afrag[m] = *(const bf16x8*)((const char*)As + row * 128 + sl);
      }
#pragma unroll
      for (int n = 0; n < 4; ++n) {
        int col = wc * 64 + n * 16 + lrow;
        bfrag[n] = *(const bf16x8*)((const char*)Bs + col * 128 + sl);
      }
#pragma unroll
      for (int m = 0; m < 4; ++m)
#pragma unroll
        for (int n = 0; n < 4; ++n)
          acc[m][n] = __builtin_amdgcn_mfma_f32_16x16x32_bf16(
              afrag[m], bfrag[n], acc[m][n], 0, 0, 0);
    }
  }

  const int lcol  = lane & 15;
  const int lrow4 = (lane >> 4) * 4;
#pragma unroll
  for (int m = 0; m < 4; ++m) {
    int rowbase = bm + wr * 64 + m * 16 + lrow4;
#pragma unroll
    for (int n = 0; n < 4; ++n) {
      int col = bn + wc * 64 + n * 16 + lcol;
      float bv = bias[col];
#pragma unroll
      for (int j = 0; j < 4; ++j) {
        int row = rowbase + j;
        Cout[(size_t)row * CH_ + col] = f2bf(acc[m][n][j] + bv);
      }
    }
  }
}

// ---------------------------------------------------------------------------
// O-proj: pure N-tiled GEMM + residual, fp32 out (in-place X).
// 128x128 tile, BK=64 (8 barrier-pairs), slot-XOR swizzle both sides.
// Grid 320 = 8 xcd x 4 cb x 10 rb.
// ---------------------------------------------------------------------------
__global__ __launch_bounds__(256)
void gemm_oproj(const u16* __restrict__ A, const u16* __restrict__ Bw,
                const float* __restrict__ bias, float* __restrict__ Xio) {
  __shared__ __align__(16) u16 As[128 * QBK];   // 16KB
  __shared__ __align__(16) u16 Bs[128 * QBK];   // 16KB
  const int tid = threadIdx.x;
  const int wid = tid >> 6;
  const int lane = tid & 63;
  const int bid = blockIdx.x;
  const int xcd = bid & 7;
  const int t = bid >> 3;                 // 0..39
  const int cb = t & 3;
  const int rb = xcd * 10 + (t >> 2);
  const int bm = rb * 128;
  const int bn = cb * 128;
  const int wr = wid >> 1, wc = wid & 1;

  const int srow = tid >> 3;                          // 0..31
  const int sko  = (((tid & 7) ^ (srow & 7)) << 3);

  f32x4 acc[4][4] = {};

  const u16* AgS = A  + (size_t)(bm + srow) * D_ + sko;
  const u16* BgS = Bw + (size_t)(bn + srow) * D_ + sko;
  u16* AsS = &As[wid * 512];
  u16* BsS = &Bs[wid * 512];

  const int lrow = lane & 15;
  const int lg   = lane >> 4;

  for (int k0 = 0; k0 < D_; k0 += QBK) {
    __syncthreads();
#pragma unroll
    for (int r = 0; r < 4; ++r) {
      gload_lds16(AgS + (size_t)(r * 32) * D_ + k0, AsS + r * 2048);
      gload_lds16(BgS + (size_t)(r * 32) * D_ + k0, BsS + r * 2048);
    }
    __syncthreads();

#pragma unroll
    for (int kk = 0; kk < 2; ++kk) {
      const int sl = (((kk * 4) + lg) ^ (lrow & 7)) << 4;
      bf16x8 afrag[4], bfrag[4];
#pragma unroll
      for (int m = 0; m < 4; ++m) {
        int row = wr * 64 + m * 16 + lrow;
        afrag[m] = *(const bf16x8*)((const char*)As + row * 128 + sl);
      }
#pragma unroll
      for (int n = 0; n < 4; ++n) {
        int col = wc * 64 + n * 16 + lrow;
        bfrag[n] = *(const bf16x8*)((const char*)Bs + col * 128 + sl);
      }
#pragma unroll
      for (int m = 0; m < 4; ++m)
#pragma unroll
        for (int n = 0; n < 4; ++n)
          acc[m][n] = __builtin_amdgcn_mfma_f32_16x16x32_bf16(
              afrag[m], bfrag[n], acc[m][n], 0, 0, 0);
    }
  }

  const int lcol  = lane & 15;
  const int lrow4 = (lane >> 4) * 4;
#pragma unroll
  for (int m = 0; m < 4; ++m) {
    int rowbase = bm + wr * 64 + m * 16 + lrow4;
#pragma unroll
    for (int n = 0; n < 4; ++n) {
      int col = bn + wc * 64 + n * 16 + lcol;
      float bv = bias[col];
#pragma unroll
      for (int j = 0; j < 4; ++j) {
        size_t idx = (size_t)(rowbase + j) * D_ + col;
        Xio[idx] = acc[m][n][j] + bv + Xio[idx];
      }
    }
  }
}

// ---------------------------------------------------------------------------
// Fused FFN: LN_ff (register prologue) -> FFN1(relu, H in regs->LDS) ->
// FFN2 + residual + LN_out (+ LN_in next). 16-row tiles, grid 640.
// Phase A now BK=64 (8 barrier-pairs, 4 MFMA each) with slot-XOR-swizzled
// W1 tile [128][64] (both sides, G21); A-operand from resident Aln.
// MODE 1 (l<3): LN1 -> Xout fp32; LN2 -> OutBf bf16.   MODE 2: LN1 only.
// ---------------------------------------------------------------------------
template <int MODE>
__global__ __launch_bounds__(256)
void ffn_fused(const float* __restrict__ X,
               const float* __restrict__ gff, const float* __restrict__ bff,
               const u16* __restrict__ W1, const float* __restrict__ b1,
               const u16* __restrict__ W2, const float* __restrict__ b2,
               const float* __restrict__ g1, const float* __restrict__ b1o,
               const float* __restrict__ g2, const float* __restrict__ b2i,
               float* __restrict__ Xout, u16* __restrict__ OutBf) {
  __shared__ __align__(16) u16 Bs[512 * 32];    // 32KB: W1 tile / W2 tile
  __shared__ __align__(16) u16 Aln[16 * 512];   // 16KB swizzled; Hs overlays
  __shared__ float wsum[4][16], wss[4][16], mu_s[16], rs_s[16];
  u16* Hs = Aln;                                // 4KB overlay (post phase A)
  const int tid = threadIdx.x;
  const int wid = tid >> 6, lane = tid & 63;
  const int bm = blockIdx.x * 16;
  const int r  = tid >> 4;            // 0..15 row in tile
  const int jj = tid & 15;            // 16 lanes per row

  // ---- LN_ff prologue (in registers) ----
  {
    const float* xr = X + (size_t)(bm + r) * D_ + jj * 32;
    float v[32];
    float s = 0.f, ss = 0.f;
#pragma unroll
    for (int i = 0; i < 8; ++i) {
      float4 q = *(const float4*)(xr + i * 4);
      v[i * 4 + 0] = q.x; v[i * 4 + 1] = q.y;
      v[i * 4 + 2] = q.z; v[i * 4 + 3] = q.w;
      s  += q.x + q.y + q.z + q.w;
      ss += q.x * q.x + q.y * q.y + q.z * q.z + q.w * q.w;
    }
#pragma unroll
    for (int off = 1; off < 16; off <<= 1) {
      s  += __shfl_xor(s, off);
      ss += __shfl_xor(ss, off);
    }
    float mu = s * (1.0f / D_);
    float var = ss * (1.0f / D_) - mu * mu;
    if (var < 0.f) var = 0.f;
    float rs = rsqrtf(var + 1e-5f);
    char* Ab = (char*)Aln;
#pragma unroll
    for (int i = 0; i < 8; ++i) {
      int c0 = jj * 32 + i * 4;
      float4 g4 = *(const float4*)(gff + c0);
      float4 b4 = *(const float4*)(bff + c0);
      ushort4 o;
      o.x = f2bf((v[i * 4 + 0] - mu) * rs * g4.x + b4.x);
      o.y = f2bf((v[i * 4 + 1] - mu) * rs * g4.y + b4.y);
      o.z = f2bf((v[i * 4 + 2] - mu) * rs * g4.z + b4.z);
      o.w = f2bf((v[i * 4 + 3] - mu) * rs * g4.w + b4.w);
      int byteoff = (r * 1024 + c0 * 2) ^ ((r & 7) << 4);
      *(ushort4*)(Ab + byteoff) = o;
    }
  }
  __syncthreads();

  // ---- phase A: H = relu(LN_ff @ W1^T + b1), BK=64 ----
  const int lrow = lane & 15;
  const int lko  = (lane >> 4) << 4;   // bytes
  const int lg   = lane >> 4;          // k-group 0..3
  const int l4 = lane >> 2;
  const int k8 = (lane & 3) << 3;
  // BK=64 staging: chunk = r*256+tid; row = r*32+(tid>>3); slot round-indep:
  const int srowA = tid >> 3;                          // 0..31 (+r*32)
  const int skoA  = (((tid & 7) ^ (srowA & 7)) << 3);  // element offset
  f32x4 accA[2] = {};

  for (int k0 = 0; k0 < D_; k0 += 64) {
    if (k0) __syncthreads();
    // stage W1 rows [0,128) x k [k0,k0+64): 16KB, 4 rounds x 256 thr
#pragma unroll
    for (int rr = 0; rr < 4; ++rr) {
      gload_lds16(W1 + (size_t)(rr * 32 + srowA) * D_ + k0 + skoA,
                  Bs + (size_t)(rr * 256 + wid * 64) * 8);
    }
    __syncthreads();
#pragma unroll
    for (int kk = 0; kk < 2; ++kk) {
      bf16x8 af = *(const bf16x8*)((const char*)Aln +
                    ((lrow * 1024 + (k0 + kk * 32) * 2 + lko) ^ ((lrow & 7) << 4)));
      const int sl = (((kk * 4) + lg) ^ (lrow & 7)) << 4;
      bf16x8 bf[2];
#pragma unroll
      for (int n = 0; n < 2; ++n) {
        int row = wid * 32 + n * 16 + lrow;
        bf[n] = *(const bf16x8*)((const char*)Bs + row * 128 + sl);
      }
#pragma unroll
      for (int n = 0; n < 2; ++n)
        accA[n] = __builtin_amdgcn_mfma_f32_16x16x32_bf16(af, bf[n], accA[n], 0, 0, 0);
    }
  }

  const int lcol = lane & 15;
  const int lr4 = (lane >> 4) * 4;
  __syncthreads();                     // all Aln/Bs reads complete

  // ---- hand H to LDS (bias + relu, swizzled; overlays Aln) ----
#pragma unroll
  for (int n = 0; n < 2; ++n) {
    int col = wid * 32 + n * 16 + lcol;
    float bv = b1[col];
#pragma unroll
    for (int j = 0; j < 4; ++j) {
      int rr = lr4 + j;
      float hv = fmaxf(accA[n][j] + bv, 0.f);
      int byteoff = (rr * 256 + col * 2) ^ ((rr & 7) << 4);
      *(u16*)((char*)Hs + byteoff) = f2bf(hv);
    }
  }

  // ---- phase B: FFN2 + residual + LN_out (+ LN_in) ----
  f32x4 acc[8] = {};
  for (int k0 = 0; k0 < FFN_; k0 += 32) {
    __syncthreads();                   // k0=0: Hs visible; else: reads done
#pragma unroll
    for (int p = 0; p < 8; ++p) {
      int row = wid * 128 + p * 16 + l4;
      gload_lds16(W2 + (size_t)row * FFN_ + k0 + k8,
                  (char*)Bs + (wid * 128 + p * 16) * 64);
    }
    __syncthreads();

    bf16x8 af = *(const bf16x8*)((const char*)Hs +
                  ((lrow * 256 + k0 * 2 + lko) ^ ((lrow & 7) << 4)));
    bf16x8 bf[8];
#pragma unroll
    for (int n = 0; n < 8; ++n)
      bf[n] = *(const bf16x8*)((const char*)Bs + (wid * 128 + n * 16 + lrow) * 64 + lko);
#pragma unroll
    for (int n = 0; n < 8; ++n)
      acc[n] = __builtin_amdgcn_mfma_f32_16x16x32_bf16(af, bf[n], acc[n], 0, 0, 0);
  }

  // ---- bias + residual ----
#pragma unroll
  for (int n = 0; n < 8; ++n) {
    int col = wid * 128 + n * 16 + lcol;
    float bv = b2[col];
#pragma unroll
    for (int j = 0; j < 4; ++j) {
      int row = bm + lr4 + j;
      acc[n][j] = acc[n][j] + bv + X[(size_t)row * D_ + col];
    }
  }

  // ---- LN pass 1 (ln_out) ----
  {
    float s0[4] = {}, s1[4] = {};
#pragma unroll
    for (int n = 0; n < 8; ++n)
#pragma unroll
      for (int j = 0; j < 4; ++j) {
        float v = acc[n][j];
        s0[j] += v; s1[j] += v * v;
      }
#pragma unroll
    for (int off = 1; off < 16; off <<= 1)
#pragma unroll
      for (int j = 0; j < 4; ++j) {
        s0[j] += __shfl_xor(s0[j], off);
        s1[j] += __shfl_xor(s1[j], off);
      }
    if ((lane & 15) == 0) {
#pragma unroll
      for (int j = 0; j < 4; ++j) {
        wsum[wid][lr4 + j] = s0[j]; wss[wid][lr4 + j] = s1[j];
      }
    }
  }
  __syncthreads();
  if (tid < 16) {
    float S  = wsum[0][tid] + wsum[1][tid] + wsum[2][tid] + wsum[3][tid];
    float SS = wss[0][tid] + wss[1][tid] + wss[2][tid] + wss[3][tid];
    float mu = S * (1.0f / D_);
    float var = SS * (1.0f / D_) - mu * mu;
    if (var < 0.f) var = 0.f;
    mu_s[tid] = mu; rs_s[tid] = rsqrtf(var + 1e-5f);
  }
  __syncthreads();

  float gg[8], bv2[8];
#pragma unroll
  for (int n = 0; n < 8; ++n) {
    int col = wid * 128 + n * 16 + lcol;
    gg[n] = g1[col]; bv2[n] = b1o[col];
  }
#pragma unroll
  for (int n = 0; n < 8; ++n) {
    int col = wid * 128 + n * 16 + lcol;
#pragma unroll
    for (int j = 0; j < 4; ++j) {
      int rr = lr4 + j;
      int row = bm + rr;
      float ln = (acc[n][j] - mu_s[rr]) * rs_s[rr] * gg[n] + bv2[n];
      Xout[(size_t)row * D_ + col] = ln;
      acc[n][j] = ln;
    }
  }

  if (MODE == 1) {
    // ---- LN pass 2 (ln_in next layer) ----
    __syncthreads();
    {
      float s0[4] = {}, s1[4] = {};
#pragma unroll
      for (int n = 0; n < 8; ++n)
#pragma unroll
        for (int j = 0; j < 4; ++j) {
          float v = acc[n][j];
          s0[j] += v; s1[j] += v * v;
        }
#pragma unroll
      for (int off = 1; off < 16; off <<= 1)
#pragma unroll
        for (int j = 0; j < 4; ++j) {
          s0[j] += __shfl_xor(s0[j], off);
          s1[j] += __shfl_xor(s1[j], off);
        }
      if ((lane & 15) == 0) {
#pragma unroll
        for (int j = 0; j < 4; ++j) {
          wsum[wid][lr4 + j] = s0[j]; wss[wid][lr4 + j] = s1[j];
        }
      }
    }
    __syncthreads();
    if (tid < 16) {
      float S  = wsum[0][tid] + wsum[1][tid] + wsum[2][tid] + wsum[3][tid];
      float SS = wss[0][tid] + wss[1][tid] + wss[2][tid] + wss[3][tid];
      float mu = S * (1.0f / D_);
      float var = SS * (1.0f / D_) - mu * mu;
      if (var < 0.f) var = 0.f;
      mu_s[tid] = mu; rs_s[tid] = rsqrtf(var + 1e-5f);
    }
    __syncthreads();
#pragma unroll
    for (int n = 0; n < 8; ++n) {
      int col = wid * 128 + n * 16 + lcol;
      gg[n] = g2[col]; bv2[n] = b2i[col];
    }
#pragma unroll
    for (int n = 0; n < 8; ++n) {
      int col = wid * 128 + n * 16 + lcol;
#pragma unroll
      for (int j = 0; j < 4; ++j) {
        int rr = lr4 + j;
        int row = bm + rr;
        float ln = (acc[n][j] - mu_s[rr]) * rs_s[rr] * gg[n] + bv2[n];
        OutBf[(size_t)row * D_ + col] = f2bf(ln);
      }
    }
  }
}

// ---------------------------------------------------------------------------
// Block-diagonal attention reading fused QKV (stride 1536), f32 LDS,
// vectorized loads. Scale pre-folded into Wq/bq. One block per (b, seg);
// wave h = head h. Segment rows: {s, 256+4s..+3}.
// ---------------------------------------------------------------------------
#define QLD 516
__global__ __launch_bounds__(256)
void attn_k(const u16* __restrict__ QKV, u16* __restrict__ O) {
  int bs = blockIdx.x;
  int b = bs >> 8, s = bs & 255;
  __shared__ float Qs[5][QLD];
  __shared__ float Ks[5][QLD];
  __shared__ float Vs[5][QLD];
  __shared__ float P[H_][5][5];
  int tid = threadIdx.x;
  int rows[5];
  rows[0] = s;
#pragma unroll
  for (int i = 1; i < 5; ++i) rows[i] = R_ + 4 * s + (i - 1);
  // 960 chunks of 8 bf16: mtx (Q/K/V) x 5 rows x 64 chunks
  for (int idx = tid; idx < 960; idx += 256) {
    int mtx = idx / 320;
    int rem = idx - mtx * 320;
    int i = rem >> 6, c8 = rem & 63;
    size_t base = ((size_t)b * TOT_ + rows[i]) * CH_ + mtx * 512 + c8 * 8;
    bf16x8 v = *(const bf16x8*)(QKV + base);
    float* dst = (mtx == 0) ? &Qs[i][c8 * 8] : (mtx == 1 ? &Ks[i][c8 * 8] : &Vs[i][c8 * 8]);
#pragma unroll
    for (int t = 0; t < 8; ++t) dst[t] = bf2f((u16)v[t]);
  }
  __syncthreads();
  int h = tid >> 6, lane = tid & 63;
  if (lane < 25) {
    int i = lane / 5, j = lane % 5;
    float sum = 0.f;
    const float* qp = &Qs[i][h * DH_];
    const float* kp = &Ks[j][h * DH_];
#pragma unroll 8
    for (int d = 0; d < DH_; ++d) sum += qp[d] * kp[d];
    P[h][i][j] = sum;
  }
  __syncthreads();
  if (lane < 5) {
    int i = lane;
    float m = P[h][i][0];
#pragma unroll
    for (int j = 1; j < 5; ++j) m = fmaxf(m, P[h][i][j]);
    float e[5], ssum = 0.f;
#pragma unroll
    for (int j = 0; j < 5; ++j) { e[j] = __expf(P[h][i][j] - m); ssum += e[j]; }
    float inv = 1.0f / ssum;
#pragma unroll
    for (int j = 0; j < 5; ++j) P[h][i][j] = e[j] * inv;
  }
  __syncthreads();
  for (int idx = lane; idx < 5 * DH_; idx += 64) {
    int i = idx >> 7, d = idx & (DH_ - 1);
    float o = 0.f;
#pragma unroll
    for (int j = 0; j < 5; ++j) o += P[h][i][j] * Vs[j][h * DH_ + d];
    O[((size_t)b * TOT_ + rows[i]) * D_ + h * DH_ + d] = f2bf(o);
  }
}

// ---------------------------------------------------------------------------
// mean over the 1024 u rows -> (B, D), two stages (128 + 16 blocks).
// ---------------------------------------------------------------------------
__global__ __launch_bounds__(256)
void mean_part_k(const float* __restrict__ X, float* __restrict__ part) {
  int d = blockIdx.x * 256 + threadIdx.x;
  int jc = blockIdx.y;
  int b = blockIdx.z;
  float acc = 0.f;
  const float* base = X + ((size_t)b * TOT_ + R_ + jc * 128) * D_ + d;
  for (int j = 0; j < 128; ++j) acc += base[(size_t)j * D_];
  part[((size_t)b * 8 + jc) * D_ + d] = acc;
}

__global__ __launch_bounds__(256)
void mean_final_k(const float* __restrict__ part, float* __restrict__ out) {
  int i = blockIdx.x * 256 + threadIdx.x;
  int b = i >> 9, d = i & (D_ - 1);
  float acc = 0.f;
#pragma unroll
  for (int c = 0; c < 8; ++c) acc += part[((size_t)b * 8 + c) * D_ + d];
  out[i] = acc * (1.0f / U_);
}

// ---------------------------------------------------------------------------
// Launch. Workspace layout (byte offsets):
//   X      @ 0          fp32 20,971,520
//   LNbuf  @ 20971520   bf16 10,485,760
//   QKV    @ 31457280   bf16 31,457,280
//   ATT    @ 62914560   bf16 10,485,760
//   part   @ 86507520   fp32    131,072
//   WQKVb  @ 86638592   bf16  6,291,456
//   Wob    @ 92930048   bf16  2,097,152
//   W1b    @ 95027200   bf16    524,288
//   W2b    @ 95551488   bf16    524,288
//   bQKV   @ 96075776   fp32     24,576
// ---------------------------------------------------------------------------
extern "C" void kernel_launch(void* const* d_in, const int* in_sizes, int n_in,
                              void* d_out, int out_size, void* d_ws, size_t ws_size,
                              hipStream_t stream) {
  const float* x      = (const float*)d_in[0];
  const float* Wq     = (const float*)d_in[1];
  const float* bq     = (const float*)d_in[2];
  const float* Wkv    = (const float*)d_in[3];
  const float* bkv    = (const float*)d_in[4];
  const float* Wo     = (const float*)d_in[5];
  const float* bo     = (const float*)d_in[6];
  const float* W1     = (const float*)d_in[7];
  const float* b1     = (const float*)d_in[8];
  const float* W2     = (const float*)d_in[9];
  const float* b2     = (const float*)d_in[10];
  const float* ln_in_g  = (const float*)d_in[11];
  const float* ln_in_b  = (const float*)d_in[12];
  const float* ff_ln_g  = (const float*)d_in[13];
  const float* ff_ln_b  = (const float*)d_in[14];
  const float* ln_out_g = (const float*)d_in[15];
  const float* ln_out_b = (const float*)d_in[16];
  float* out = (float*)d_out;

  char* wsb = (char*)d_ws;
  float* X     = (float*)wsb;
  u16*   LNbuf = (u16*)(wsb + 20971520);
  u16*   QKV   = (u16*)(wsb + 31457280);
  u16*   ATT   = (u16*)(wsb + 62914560);
  float* part  = (float*)(wsb + 86507520);
  u16*   WQKVb = (u16*)(wsb + 86638592);
  u16*   Wob   = (u16*)(wsb + 92930048);
  u16*   W1b   = (u16*)(wsb + 95027200);
  u16*   W2b   = (u16*)(wsb + 95551488);
  float* bQKV  = (float*)(wsb + 96075776);

  // merged setup: weight cvt/pack + gather+LN-in(0)
  cvt_gather_k<<<SETUP_GRID, 256, 0, stream>>>(Wq, Wkv, Wo, W1, W2, bq, bkv,
                                               WQKVb, Wob, W1b, W2b, bQKV,
                                               x, ln_in_g, ln_in_b, X, LNbuf);

  for (int l = 0; l < L_; ++l) {
    const u16* WQKV_l = WQKVb + (size_t)l * CH_ * D_;
    const u16* Wo_l   = Wob   + (size_t)l * D_ * D_;
    const u16* W1_l   = W1b   + (size_t)l * FFN_ * D_;
    const u16* W2_l   = W2b   + (size_t)l * D_ * FFN_;
    const float* bQKV_l = bQKV + (size_t)l * CH_;
    const float* bo_l = bo + (size_t)l * D_;
    const float* b1_l = b1 + (size_t)l * FFN_;
    const float* b2_l = b2 + (size_t)l * D_;

    // QKV = LNbuf @ WQKV^T + bQKV  (BK=64, swizzled; Q pre-scaled)
    gemm_qkv<<<960, 256, 0, stream>>>(LNbuf, WQKV_l, bQKV_l, QKV);

    // attention -> ATT
    attn_k<<<B_ * NSEG_, 256, 0, stream>>>(QKV, ATT);

    // X += ATT @ Wo^T + bo  (BK=64, swizzled)
    gemm_oproj<<<320, 256, 0, stream>>>(ATT, Wo_l, bo_l, X);

    // fused FFN: LN_ff -> FFN1(relu, BK=64) -> FFN2 + X + LN_out (+LN_in)
    if (l < L_ - 1) {
      ffn_fused<1><<<M_ / 16, 256, 0, stream>>>(
          X, ff_ln_g + l * D_, ff_ln_b + l * D_,
          W1_l, b1_l, W2_l, b2_l,
          ln_out_g + l * D_, ln_out_b + l * D_,
          ln_in_g + (l + 1) * D_, ln_in_b + (l + 1) * D_,
          X, LNbuf);
    } else {
      ffn_fused<2><<<M_ / 16, 256, 0, stream>>>(
          X, ff_ln_g + l * D_, ff_ln_b + l * D_,
          W1_l, b1_l, W2_l, b2_l,
          ln_out_g + l * D_, ln_out_b + l * D_,
          nullptr, nullptr,
          X, nullptr);
    }
  }

  mean_part_k<<<dim3(2, 8, 8), 256, 0, stream>>>(X, part);
  mean_final_k<<<(B_ * D_) / 256, 256, 0, stream>>>(part, out);
}